// Round 1
// baseline (542.825 us; speedup 1.0000x reference)
//
#include <hip/hip_runtime.h>
#include <stdint.h>

#define AS1 __attribute__((address_space(1)))
#define AS3 __attribute__((address_space(3)))

typedef __bf16 bf16x8 __attribute__((ext_vector_type(8)));   // 4 VGPRs
typedef float  f32x4  __attribute__((ext_vector_type(4)));

#define MFMA16(a, b, c) __builtin_amdgcn_mfma_f32_16x16x32_bf16((a), (b), (c), 0, 0, 0)

// ---- constants for this problem ----
#define SEQ   512
#define NBAT  64
#define DM    768
#define NH    12
#define DH    64
#define NQKV  2304
#define NTOK  (NBAT * SEQ)   // 32768
#define NKB   12             // K=768 -> 12 K-tiles of 64

__device__ __forceinline__ uint16_t f2bf(float x) {          // fp32 -> bf16 RNE
  uint32_t u = __float_as_uint(x);
  return (uint16_t)((u + 0x7FFFu + ((u >> 16) & 1u)) >> 16);
}

__device__ __forceinline__ void async16(uint16_t* lds, const uint16_t* g) {
  // 16B global -> LDS direct (dest = wave-uniform base + lane*16)
  __builtin_amdgcn_global_load_lds((AS1 void*)(uintptr_t)(const void*)g,
                                   (AS3 void*)lds, 16, 0, 0);
}

// row->column XOR swizzle on 16B chunks: conflict-free fragment reads
// (measured 0 SQ_LDS_BANK_CONFLICT in this problem's GEMM + attn).
__device__ __forceinline__ int swz(int r) { return (r ^ (r >> 3)) & 7; }

// ---------------- converter: f32 -> bf16, weights to plain row-major ----------------
__global__ __launch_bounds__(256) void k_cvt(
    const float* __restrict__ tokens,
    const float* __restrict__ Wq, const float* __restrict__ Wk,
    const float* __restrict__ Wv, const float* __restrict__ Wo,
    const float* __restrict__ bq, const float* __restrict__ bk, const float* __restrict__ bv,
    uint16_t* __restrict__ X, uint16_t* __restrict__ Wqkv, uint16_t* __restrict__ Wob,
    float* __restrict__ bqkv) {
  int i = blockIdx.x * 256 + threadIdx.x;     // grid covers NTOK*DM/8 = 3,145,728
  {
    const float4* sp = (const float4*)tokens;
    float4 a = sp[2 * i], b = sp[2 * i + 1];
    union { uint16_t u[8]; uint4 v; } o;
    o.u[0] = f2bf(a.x); o.u[1] = f2bf(a.y); o.u[2] = f2bf(a.z); o.u[3] = f2bf(a.w);
    o.u[4] = f2bf(b.x); o.u[5] = f2bf(b.y); o.u[6] = f2bf(b.z); o.u[7] = f2bf(b.w);
    ((uint4*)X)[i] = o.v;
  }
  // Wqkv row-major [2304][768]: 221184 16B chunks
  if (i < 221184) {
    int row = i / 96, k = (i % 96) * 8;
    const float* src = (row < 768)  ? Wq + (size_t)row * 768 + k
                     : (row < 1536) ? Wk + (size_t)(row - 768) * 768 + k
                                    : Wv + (size_t)(row - 1536) * 768 + k;
    float4 a = *(const float4*)src, b = *(const float4*)(src + 4);
    union { uint16_t u[8]; uint4 v; } o;
    o.u[0] = f2bf(a.x); o.u[1] = f2bf(a.y); o.u[2] = f2bf(a.z); o.u[3] = f2bf(a.w);
    o.u[4] = f2bf(b.x); o.u[5] = f2bf(b.y); o.u[6] = f2bf(b.z); o.u[7] = f2bf(b.w);
    ((uint4*)Wqkv)[i] = o.v;
  }
  // Wo row-major [768][768]: 73728 chunks
  if (i < 73728) {
    int row = i / 96, k = (i % 96) * 8;
    const float* src = Wo + (size_t)row * 768 + k;
    float4 a = *(const float4*)src, b = *(const float4*)(src + 4);
    union { uint16_t u[8]; uint4 v; } o;
    o.u[0] = f2bf(a.x); o.u[1] = f2bf(a.y); o.u[2] = f2bf(a.z); o.u[3] = f2bf(a.w);
    o.u[4] = f2bf(b.x); o.u[5] = f2bf(b.y); o.u[6] = f2bf(b.z); o.u[7] = f2bf(b.w);
    ((uint4*)Wob)[i] = o.v;
  }
  if (i < 768) { bqkv[i] = bq[i]; bqkv[i + 768] = bk[i]; bqkv[i + 1536] = bv[i]; }
}

// ---------------- 256x256 8-phase GEMM: C[M,N] = A[M,768] * B[N,768]^T + bias, *rowscale ----------------
// 8 waves (2M x 4N), per-wave 128x64 output. BK=64. LDS = 8 half-tile slots
// of 128x64 bf16 (16KB each, 128KB total): tile V parity p=(V&1)*4 holds
// {A0,A1,B0,B1} at p+0..p+3. Per K-tile, 4 phases:
//   phi1: ds_read a0,b0 | stage A1(V+1)      | MFMA Q(mh0,nh0)
//   phi2: ds_read b1    | stage A0(V+2)      | MFMA Q(mh0,nh1)
//   phi3: ds_read a1    | stage B0(V+2)      | MFMA Q(mh1,nh1)
//   phi4:               | stage B1(V+2), vmcnt(6) | MFMA Q(mh1,nh0)
// Slot re-stage always >=1 barrier after that slot's last ds_read; vmcnt(6)
// (= 3 half-tiles x 2 loads in flight) guarantees tile V+1 landed before its
// first read; never drained to 0 except the last two tiles.
__global__ __launch_bounds__(512, 2) void k_gemm8(
    const uint16_t* __restrict__ A, const uint16_t* __restrict__ B,
    const float* __restrict__ bias, const float* __restrict__ rowscale,
    uint16_t* __restrict__ C, int ldc, int ncol) {
  __shared__ __align__(16) uint16_t lds[8 * 8192];   // 128 KB
  const int tid = threadIdx.x;
  const int w = tid >> 6, lane = tid & 63;
  const int wu = __builtin_amdgcn_readfirstlane(w);
  const int wm = w >> 2, wn = w & 3;
  const int l16 = lane & 15, quad = lane >> 4;

  // bijective XCD swizzle (gridDim.x % 8 == 0); row-tile-major so each XCD
  // chunk shares A panels.
  const int cpx = gridDim.x >> 3;
  const int t = (blockIdx.x & 7) * cpx + (blockIdx.x >> 3);
  const int rowt = t / ncol, colt = t - rowt * ncol;
  const int row0 = rowt << 8, col0 = colt << 8;

  // per-thread staging coords: LDS dest linear, global source pre-swizzled
  const int r0s = tid >> 3, c0s = (tid & 7) ^ swz(r0s);
  const int r1s = 64 + r0s, c1s = (tid & 7) ^ swz(r1s);

  const int rA = wm * 64 + l16;   // + mf*16 : row within A half-tile slot
  const int rB = wn * 32 + l16;   // + nf*16 : row within B half-tile slot

#define STAGE(mat, rbase, kt, slot_) do {                                      \
    async16(&lds[(slot_) * 8192 + wu * 512],                                   \
            (mat) + (size_t)((rbase) + r0s) * 768 + (kt) * 64 + c0s * 8);      \
    async16(&lds[(slot_) * 8192 + 4096 + wu * 512],                            \
            (mat) + (size_t)((rbase) + r1s) * 768 + (kt) * 64 + c1s * 8);      \
  } while (0)

  f32x4 acc[2][4][2][2] = {};        // [mh][mf][nh][nf]
  bf16x8 a0[4][2], a1[4][2], b0[2][2], b1[2][2];

  // prologue: tile0 {A0,A1,B0,B1} -> 0..3 ; tile1 {A0,B0,B1} -> 4,6,7
  // (A1(1) is staged at phi1 of tile 0 -> slot 5)
  STAGE(A, row0,       0, 0);
  STAGE(A, row0 + 128, 0, 1);
  STAGE(B, col0,       0, 2);
  STAGE(B, col0 + 128, 0, 3);
  STAGE(A, row0,       1, 4);
  STAGE(B, col0,       1, 6);
  STAGE(B, col0 + 128, 1, 7);
  asm volatile("s_waitcnt vmcnt(6)" ::: "memory");   // tile 0 (oldest 8) landed
  __builtin_amdgcn_s_barrier();
  asm volatile("" ::: "memory");

#pragma unroll 2
  for (int W = 0; W < NKB; ++W) {
    const int p = (W & 1) << 2, q = p ^ 4;
    // ---------- phase 1: a0 (p+0), b0 (p+2); stage A1(W+1) -> q+1; Q(0,0)
#pragma unroll
    for (int mf = 0; mf < 4; ++mf) {
      int r = rA + mf * 16;
#pragma unroll
      for (int kf = 0; kf < 2; ++kf) {
        int c = (kf * 4 + quad) ^ swz(r);
        a0[mf][kf] = *(const bf16x8*)&lds[(p + 0) * 8192 + r * 64 + c * 8];
      }
    }
#pragma unroll
    for (int nf = 0; nf < 2; ++nf) {
      int r = rB + nf * 16;
#pragma unroll
      for (int kf = 0; kf < 2; ++kf) {
        int c = (kf * 4 + quad) ^ swz(r);
        b0[nf][kf] = *(const bf16x8*)&lds[(p + 2) * 8192 + r * 64 + c * 8];
      }
    }
    if (W + 1 < NKB) STAGE(A, row0 + 128, W + 1, q + 1);
    __builtin_amdgcn_s_barrier();
    asm volatile("s_waitcnt lgkmcnt(0)" ::: "memory");
    __builtin_amdgcn_sched_barrier(0);
    __builtin_amdgcn_s_setprio(1);
#pragma unroll
    for (int mf = 0; mf < 4; ++mf)
#pragma unroll
      for (int nf = 0; nf < 2; ++nf)
#pragma unroll
        for (int kf = 0; kf < 2; ++kf)
          acc[0][mf][0][nf] = MFMA16(a0[mf][kf], b0[nf][kf], acc[0][mf][0][nf]);
    __builtin_amdgcn_s_setprio(0);
    __builtin_amdgcn_s_barrier();
    asm volatile("" ::: "memory");
    // ---------- phase 2: b1 (p+3); stage A0(W+2) -> p+0; Q(0,1)
#pragma unroll
    for (int nf = 0; nf < 2; ++nf) {
      int r = rB + nf * 16;
#pragma unroll
      for (int kf = 0; kf < 2; ++kf) {
        int c = (kf * 4 + quad) ^ swz(r);
        b1[nf][kf] = *(const bf16x8*)&lds[(p + 3) * 8192 + r * 64 + c * 8];
      }
    }
    if (W + 2 < NKB) STAGE(A, row0, W + 2, p + 0);
    __builtin_amdgcn_s_barrier();
    asm volatile("s_waitcnt lgkmcnt(0)" ::: "memory");
    __builtin_amdgcn_sched_barrier(0);
    __builtin_amdgcn_s_setprio(1);
#pragma unroll
    for (int mf = 0; mf < 4; ++mf)
#pragma unroll
      for (int nf = 0; nf < 2; ++nf)
#pragma unroll
        for (int kf = 0; kf < 2; ++kf)
          acc[0][mf][1][nf] = MFMA16(a0[mf][kf], b1[nf][kf], acc[0][mf][1][nf]);
    __builtin_amdgcn_s_setprio(0);
    __builtin_amdgcn_s_barrier();
    asm volatile("" ::: "memory");
    // ---------- phase 3: a1 (p+1); stage B0(W+2) -> p+2; Q(1,1)
#pragma unroll
    for (int mf = 0; mf < 4; ++mf) {
      int r = rA + mf * 16;
#pragma unroll
      for (int kf = 0; kf < 2; ++kf) {
        int c = (kf * 4 + quad) ^ swz(r);
        a1[mf][kf] = *(const bf16x8*)&lds[(p + 1) * 8192 + r * 64 + c * 8];
      }
    }
    if (W + 2 < NKB) STAGE(B, col0, W + 2, p + 2);
    __builtin_amdgcn_s_barrier();
    asm volatile("s_waitcnt lgkmcnt(0)" ::: "memory");
    __builtin_amdgcn_sched_barrier(0);
    __builtin_amdgcn_s_setprio(1);
#pragma unroll
    for (int mf = 0; mf < 4; ++mf)
#pragma unroll
      for (int nf = 0; nf < 2; ++nf)
#pragma unroll
        for (int kf = 0; kf < 2; ++kf)
          acc[1][mf][1][nf] = MFMA16(a1[mf][kf], b1[nf][kf], acc[1][mf][1][nf]);
    __builtin_amdgcn_s_setprio(0);
    __builtin_amdgcn_s_barrier();
    asm volatile("" ::: "memory");
    // ---------- phase 4: stage B1(W+2) -> p+3; counted vmcnt; Q(1,0)
    if (W + 2 < NKB) STAGE(B, col0 + 128, W + 2, p + 3);
    if (W < NKB - 2) asm volatile("s_waitcnt vmcnt(6)" ::: "memory");
    else             asm volatile("s_waitcnt vmcnt(0)" ::: "memory");
    __builtin_amdgcn_s_barrier();
    __builtin_amdgcn_sched_barrier(0);
    __builtin_amdgcn_s_setprio(1);
#pragma unroll
    for (int mf = 0; mf < 4; ++mf)
#pragma unroll
      for (int nf = 0; nf < 2; ++nf)
#pragma unroll
        for (int kf = 0; kf < 2; ++kf)
          acc[1][mf][0][nf] = MFMA16(a1[mf][kf], b0[nf][kf], acc[1][mf][0][nf]);
    __builtin_amdgcn_s_setprio(0);
    __builtin_amdgcn_s_barrier();
    asm volatile("" ::: "memory");
  }
#undef STAGE

  // epilogue: 16x16 C/D layout: col = lane&15, row = (lane>>4)*4 + reg
#pragma unroll
  for (int nh = 0; nh < 2; ++nh)
#pragma unroll
    for (int nf = 0; nf < 2; ++nf) {
      int col = col0 + nh * 128 + wn * 32 + nf * 16 + l16;
      float bv = bias[col];
#pragma unroll
      for (int mh = 0; mh < 2; ++mh)
#pragma unroll
        for (int mf = 0; mf < 4; ++mf)
#pragma unroll
          for (int rg = 0; rg < 4; ++rg) {
            int row = row0 + mh * 128 + wm * 64 + mf * 16 + quad * 4 + rg;
            float v = acc[mh][mf][nh][nf][rg] + bv;
            if (rowscale) v *= rowscale[row];
            C[(size_t)row * ldc + col] = f2bf(v);
          }
    }
}

// ---------------- fused attention (unchanged) ----------------
__global__ __launch_bounds__(256) void k_attn(
    const uint16_t* __restrict__ QKV, const float* __restrict__ ts,
    const float* __restrict__ mask, uint16_t* __restrict__ Aout) {
  __shared__ uint16_t Klds[64 * 64];        // swizzled chunks, 8KB
  __shared__ uint16_t Vt[64 * 72];          // [d][k] padded, 9KB
  __shared__ uint16_t Plds[4][32 * 72];     // per-wave P tile, stride 72, 18KB
  __shared__ float tkl[SEQ];                // ts*c2, masked -> +3e38

  const int tid = threadIdx.x, w = tid >> 6, lane = tid & 63;
  const int wu = __builtin_amdgcn_readfirstlane(w);
  const int quad = lane >> 4, l16 = lane & 15;
  int b = blockIdx.x;
  int xcd = b & 7, i = b >> 3;
  int qt = i & 3;
  int hg = xcd * 96 + (i >> 2);             // 0..767
  int n = hg / NH, h = hg % NH;
  const int q0 = qt * 128 + w * 32;
  const size_t rowbase = (size_t)n * SEQ * NQKV;

  const float c1 = 0.125f * 1.44269504f;     // scale * log2(e)
  const float c2 = 1.44269504f / 300.0f;     // log2(e) / tau

  for (int l = tid; l < SEQ; l += 256) {
    float t = ts[n * SEQ + l] * c2;
    tkl[l] = (mask[n * SEQ + l] > 0.f) ? t : 3e38f;
  }

  // Q fragments (A-operand): A[m=lane&15][k=quad*8+j]
  bf16x8 qf[2][2];
  float tq[2][4];
#pragma unroll
  for (int qs = 0; qs < 2; ++qs) {
    int qr = q0 + qs * 16 + l16;
    const uint16_t* qp = QKV + rowbase + (size_t)qr * NQKV + h * DH;
#pragma unroll
    for (int dsp = 0; dsp < 2; ++dsp)
      qf[qs][dsp] = *(const bf16x8*)(qp + dsp * 32 + quad * 8);
#pragma unroll
    for (int rg = 0; rg < 4; ++rg)
      tq[qs][rg] = ts[n * SEQ + q0 + qs * 16 + quad * 4 + rg] * c2;
  }

  f32x4 accO[2][4] = {};
  f32x4 accL[2] = {};
  bf16x8 ones_b;
  {
    union { uint16_t u[8]; bf16x8 v; } t;
    uint16_t o = (l16 == 0) ? 0x3F80 : 0;   // bf16 1.0 in column 0 only
#pragma unroll
    for (int j = 0; j < 8; ++j) t.u[j] = o;
    ones_b = t.v;
  }
  uint16_t* Pw = &Plds[w][0];

  for (int k0 = 0; k0 < SEQ; k0 += 64) {
    __syncthreads();
    // stage K rows (row-major 64x64, swz-swizzled) via global_load_lds
#pragma unroll
    for (int j = 0; j < 2; ++j) {
      int cid = j * 256 + w * 64 + lane;      // 0..511
      int r = cid >> 3, cc = cid & 7, c = cc ^ swz(r);
      const uint16_t* g = QKV + rowbase + (size_t)(k0 + r) * NQKV + DM + h * DH + c * 8;
      async16(&Klds[(j * 256 + wu * 64) * 8], g);
    }
    // stage V transposed: Vt[d][k]
    {
      int r = tid & 63, db = (tid >> 6) * 16;
      const uint16_t* g = QKV + rowbase + (size_t)(k0 + r) * NQKV + 2 * DM + h * DH + db;
      union { uint4 v; uint16_t u[8]; } a0, a1;
      a0.v = *(const uint4*)g;
      a1.v = *(const uint4*)(g + 8);
#pragma unroll
      for (int j = 0; j < 8; ++j) Vt[(db + j) * 72 + r] = a0.u[j];
#pragma unroll
      for (int j = 0; j < 8; ++j) Vt[(db + 8 + j) * 72 + r] = a1.u[j];
    }
    __syncthreads();

#pragma unroll
    for (int kt = 0; kt < 2; ++kt) {
      // S = Q K^T over this 32-col k-tile; columns interleaved: n -> k = 2*(lane&15)+ksu
      f32x4 s[2][2] = {};
#pragma unroll
      for (int dsp = 0; dsp < 2; ++dsp) {
        bf16x8 kf[2];
#pragma unroll
        for (int ksu = 0; ksu < 2; ++ksu) {
          int r = kt * 32 + 2 * l16 + ksu;
          int c = (dsp * 4 + quad) ^ swz(r);
          kf[ksu] = *(const bf16x8*)&Klds[r * 64 + c * 8];
        }
#pragma unroll
        for (int qs = 0; qs < 2; ++qs)
#pragma unroll
          for (int ksu = 0; ksu < 2; ++ksu)
            s[qs][ksu] = MFMA16(qf[qs][dsp], kf[ksu], s[qs][ksu]);
      }
      // bias + exp + pack to bf16 pairs -> Plds[q][k] (natural k order)
      float tk0 = tkl[k0 + kt * 32 + 2 * l16];
      float tk1 = tkl[k0 + kt * 32 + 2 * l16 + 1];
#pragma unroll
      for (int qs = 0; qs < 2; ++qs) {
#pragma unroll
        for (int rg = 0; rg < 4; ++rg) {
          float d0 = fabsf(tq[qs][rg] - tk0);
          float d1 = fabsf(tq[qs][rg] - tk1);
          float p0 = __builtin_amdgcn_exp2f(fmaf(s[qs][0][rg], c1, -d0));
          float p1 = __builtin_amdgcn_exp2f(fmaf(s[qs][1][rg], c1, -d1));
          uint32_t u = (__float_as_uint(p0) >> 16) | (__float_as_uint(p1) & 0xFFFF0000u);
          *(uint32_t*)(Pw + (qs * 16 + quad * 4 + rg) * 72 + kt * 32 + 2 * l16) = u;
        }
      }
      // PV (+ ones column for row-sums). Wave-private LDS: per-wave in-order, no barrier.
      bf16x8 vb[4];
#pragma unroll
      for (int dt = 0; dt < 4; ++dt)
        vb[dt] = *(const bf16x8*)&Vt[(dt * 16 + l16) * 72 + kt * 32 + quad * 8];
#pragma unroll
      for (int qs = 0; qs < 2; ++qs) {
        bf16x8 pa = *(const bf16x8*)(Pw + (qs * 16 + l16) * 72 + kt * 32 + quad * 8);
#pragma unroll
        for (int dt = 0; dt < 4; ++dt)
          accO[qs][dt] = MFMA16(pa, vb[dt], accO[qs][dt]);
        accL[qs] = MFMA16(pa, ones_b, accL[qs]);
      }
    }
  }
  // epilogue: O = accO / l ; l lives in column 0 (lane quad*16) of accL
#pragma unroll
  for (int qs = 0; qs < 2; ++qs) {
    float inv[4];
#pragma unroll
    for (int rg = 0; rg < 4; ++rg) {
      float lv = __shfl(accL[qs][rg], lane & 48, 64);
      inv[rg] = 1.0f / lv;
    }
#pragma unroll
    for (int dt = 0; dt < 4; ++dt) {
#pragma unroll
      for (int rg = 0; rg < 4; ++rg) {
        int qr = q0 + qs * 16 + quad * 4 + rg;
        float v = accO[qs][dt][rg] * inv[rg];
        Aout[(size_t)(n * SEQ + qr) * DM + h * DH + dt * 16 + l16] = f2bf(v);
      }
    }
  }
}

// ---------------- readout pooling (unchanged) ----------------
__global__ __launch_bounds__(256) void k_pool(
    const uint16_t* __restrict__ Out, const float* __restrict__ mask,
    const float* __restrict__ readout, float* __restrict__ dst) {
  __shared__ float rsl[64];
  __shared__ float ex[SEQ];
  __shared__ float red[4];
  __shared__ float part[8][64];
  int b = blockIdx.x;
  int n = b / NH, h = b % NH;
  int tid = threadIdx.x;
  if (tid < 64) rsl[tid] = readout[h * DH + tid];
  __syncthreads();

  float suml = 0.f;
  for (int l = tid; l < SEQ; l += 256) {
    const uint16_t* rowp = Out + (size_t)(n * SEQ + l) * DM + h * DH;
    float acc = 0.f;
#pragma unroll
    for (int c = 0; c < 8; ++c) {
      union { uint4 v; uint16_t u[8]; } t;
      t.v = *(const uint4*)(rowp + c * 8);
#pragma unroll
      for (int j = 0; j < 8; ++j)
        acc += __uint_as_float(((uint32_t)t.u[j]) << 16) * rsl[c * 8 + j];
    }
    float e = __builtin_amdgcn_exp2f(acc * (0.125f * 1.44269504f));
    e = (mask[n * SEQ + l] > 0.f) ? e : 0.f;
    ex[l] = e;
    suml += e;
  }
#pragma unroll
  for (int off = 32; off; off >>= 1) suml += __shfl_down(suml, off, 64);
  if ((tid & 63) == 0) red[tid >> 6] = suml;
  __syncthreads();
  float inv = 1.0f / (red[0] + red[1] + red[2] + red[3]);

  int d0 = (tid & 31) * 2, ch = tid >> 5;
  float a0 = 0.f, a1 = 0.f;
  for (int l = ch * 64; l < ch * 64 + 64; ++l) {
    uint32_t pv = *(const uint32_t*)(Out + (size_t)(n * SEQ + l) * DM + h * DH + d0);
    float e = ex[l];
    a0 = fmaf(__uint_as_float(pv << 16), e, a0);
    a1 = fmaf(__uint_as_float(pv & 0xFFFF0000u), e, a1);
  }
  part[ch][d0] = a0;
  part[ch][d0 + 1] = a1;
  __syncthreads();
  if (tid < 64) {
    float s = 0.f;
#pragma unroll
    for (int c = 0; c < 8; ++c) s += part[c][tid];
    dst[n * DM + h * DH + tid] = s * inv;
  }
}

// ---------------- launch ----------------
extern "C" void kernel_launch(void* const* d_in, const int* in_sizes, int n_in,
                              void* d_out, int out_size, void* d_ws, size_t ws_size,
                              hipStream_t stream) {
  const float* tokens  = (const float*)d_in[0];
  const float* ts      = (const float*)d_in[1];
  const float* mask    = (const float*)d_in[2];
  const float* Wq      = (const float*)d_in[3];
  const float* bq      = (const float*)d_in[4];
  const float* Wk      = (const float*)d_in[5];
  const float* bk      = (const float*)d_in[6];
  const float* Wv      = (const float*)d_in[7];
  const float* bv      = (const float*)d_in[8];
  const float* Wo      = (const float*)d_in[9];
  const float* bo      = (const float*)d_in[10];
  const float* readout = (const float*)d_in[11];

  char* ws = (char*)d_ws;
  uint16_t* X    = (uint16_t*)ws;                   // 50,331,648 B ; reused as attn_out
  uint16_t* Wqkv = (uint16_t*)(ws + 50331648);      //  3,538,944 B (row-major)
  uint16_t* Wob  = (uint16_t*)(ws + 53870592);      //  1,179,648 B (row-major)
  float*    bqkv = (float*)   (ws + 55050240);      //      9,216 B
  uint16_t* QKV  = (uint16_t*)(ws + 55059456);      // 150,994,944 B ; reused as Out
  uint16_t* attn = X;
  uint16_t* Outb = QKV;

  k_cvt<<<12288, 256, 0, stream>>>(tokens, Wq, Wk, Wv, Wo, bq, bk, bv, X, Wqkv, Wob, bqkv);
  k_gemm8<<<1152, 512, 0, stream>>>(X, Wqkv, bqkv, nullptr, QKV, NQKV, 9);
  k_attn<<<3072, 256, 0, stream>>>(QKV, ts, mask, attn);
  k_gemm8<<<384, 512, 0, stream>>>(attn, Wob, bo, mask, Outb, DM, 3);
  k_pool<<<768, 256, 0, stream>>>(Outb, mask, readout, (float*)d_out);
}

// Round 2
// 531.242 us; speedup vs baseline: 1.0218x; 1.0218x over previous
//
#include <hip/hip_runtime.h>
#include <stdint.h>

#define AS1 __attribute__((address_space(1)))
#define AS3 __attribute__((address_space(3)))

typedef __bf16 bf16x8 __attribute__((ext_vector_type(8)));   // 4 VGPRs
typedef float  f32x4  __attribute__((ext_vector_type(4)));
typedef float  f32x16 __attribute__((ext_vector_type(16)));

#define MFMA16(a, b, c) __builtin_amdgcn_mfma_f32_16x16x32_bf16((a), (b), (c), 0, 0, 0)
#define MFMA32(a, b, c) __builtin_amdgcn_mfma_f32_32x32x16_bf16((a), (b), (c), 0, 0, 0)

// ---- constants for this problem ----
#define SEQ   512
#define NBAT  64
#define DM    768
#define NH    12
#define DH    64
#define NQKV  2304
#define NTOK  (NBAT * SEQ)   // 32768
#define NKB   12             // K=768 -> 12 K-tiles of 64

__device__ __forceinline__ uint16_t f2bf(float x) {          // fp32 -> bf16 RNE
  uint32_t u = __float_as_uint(x);
  return (uint16_t)((u + 0x7FFFu + ((u >> 16) & 1u)) >> 16);
}

__device__ __forceinline__ void async16(uint16_t* lds, const uint16_t* g) {
  // 16B global -> LDS direct (dest = wave-uniform base + lane*16)
  __builtin_amdgcn_global_load_lds((AS1 void*)(uintptr_t)(const void*)g,
                                   (AS3 void*)lds, 16, 0, 0);
}

// row->column XOR swizzle: conflict-free for the 32-row (l32/kh-split) MFMA
// fragment reads used below (measured 0 SQ_LDS_BANK_CONFLICT).
__device__ __forceinline__ int swz(int r) { return (r ^ (r >> 3)) & 7; }

// ---------------- merged converter + weight fragment-packing ----------------
// Packed layout: 16B chunk index ((g*NKB + kb)*4 + ks)*64 + lane holds
// B[row = g*32 + (lane&31)][k = kb*64 + ks*16 + (lane>>5)*8 .. +8) as bf16.
// A wave's per-(kb,ks) fragment load = 64 consecutive chunks = 1KB contiguous.
__global__ __launch_bounds__(256) void k_cvt(
    const float* __restrict__ tokens,
    const float* __restrict__ Wq, const float* __restrict__ Wk,
    const float* __restrict__ Wv, const float* __restrict__ Wo,
    const float* __restrict__ bq, const float* __restrict__ bk, const float* __restrict__ bv,
    uint16_t* __restrict__ X, uint16_t* __restrict__ Wqkv_pk, uint16_t* __restrict__ Wob_pk,
    float* __restrict__ bqkv) {
  int i = blockIdx.x * 256 + threadIdx.x;     // grid covers NTOK*DM/8 = 3,145,728
  {
    const float4* sp = (const float4*)tokens;
    float4 a = sp[2 * i], b = sp[2 * i + 1];
    union { uint16_t u[8]; uint4 v; } o;
    o.u[0] = f2bf(a.x); o.u[1] = f2bf(a.y); o.u[2] = f2bf(a.z); o.u[3] = f2bf(a.w);
    o.u[4] = f2bf(b.x); o.u[5] = f2bf(b.y); o.u[6] = f2bf(b.z); o.u[7] = f2bf(b.w);
    ((uint4*)X)[i] = o.v;
  }
  // Wqkv pack: 2304*768/8 = 221184 chunks
  if (i < 221184) {
    int lane = i & 63, ks = (i >> 6) & 3, kb = (i >> 8) % NKB, g = i / 3072;
    int row = g * 32 + (lane & 31);
    int k   = kb * 64 + ks * 16 + (lane >> 5) * 8;
    const float* src = (row < 768)  ? Wq + (size_t)row * 768 + k
                     : (row < 1536) ? Wk + (size_t)(row - 768) * 768 + k
                                    : Wv + (size_t)(row - 1536) * 768 + k;
    float4 a = *(const float4*)src, b = *(const float4*)(src + 4);
    union { uint16_t u[8]; uint4 v; } o;
    o.u[0] = f2bf(a.x); o.u[1] = f2bf(a.y); o.u[2] = f2bf(a.z); o.u[3] = f2bf(a.w);
    o.u[4] = f2bf(b.x); o.u[5] = f2bf(b.y); o.u[6] = f2bf(b.z); o.u[7] = f2bf(b.w);
    ((uint4*)Wqkv_pk)[i] = o.v;
  }
  // Wo pack: 768*768/8 = 73728 chunks
  if (i < 73728) {
    int lane = i & 63, ks = (i >> 6) & 3, kb = (i >> 8) % NKB, g = i / 3072;
    int row = g * 32 + (lane & 31);
    int k   = kb * 64 + ks * 16 + (lane >> 5) * 8;
    const float* src = Wo + (size_t)row * 768 + k;
    float4 a = *(const float4*)src, b = *(const float4*)(src + 4);
    union { uint16_t u[8]; uint4 v; } o;
    o.u[0] = f2bf(a.x); o.u[1] = f2bf(a.y); o.u[2] = f2bf(a.z); o.u[3] = f2bf(a.w);
    o.u[4] = f2bf(b.x); o.u[5] = f2bf(b.y); o.u[6] = f2bf(b.z); o.u[7] = f2bf(b.w);
    ((uint4*)Wob_pk)[i] = o.v;
  }
  if (i < 768) { bqkv[i] = bq[i]; bqkv[i + 768] = bk[i]; bqkv[i + 1536] = bv[i]; }
}

// ---------------- GEMM: C[M,N] = A[M,768] * B[N,768]^T + bias(col), optional *rowscale(row) ----------------
// R7 structure (128x128 tile, BK=64, 4 waves, B fragment-packed -> registers
// from L2) + R9 change: A double-buffered in LDS, ONE raw s_barrier per
// K-step with counted s_waitcnt vmcnt(8) (stage loads retire, the 8 B-loads
// stay in flight across the barrier; compiler inserts the B-use wait inside
// the compute phase). Removes the per-iter full vmcnt(0)+lgkmcnt(0) drain
// that capped the old structure at ~33% MfmaUtil.
// Hazards:
//  RAW buf[cur]:  per-wave issue order ... STAGE(kb)[4], B(kb)[8] -> vmcnt(8)
//                 retires STAGE(kb); then s_barrier.
//  WAR buf[cur^1]: lgkmcnt(0) before the barrier drains prev-iter ds_reads;
//                 STAGE(kb+1) is issued only after the barrier.
//  sched_barrier(0) after the barrier pins this iter's ds_reads behind it.
__global__ __launch_bounds__(256) void k_gemm_bt(
    const uint16_t* __restrict__ A, const uint16_t* __restrict__ Bpk,
    const float* __restrict__ bias, const float* __restrict__ rowscale,
    uint16_t* __restrict__ C, int ldc, int ncol) {
  __shared__ __align__(16) uint16_t Alds[2][128 * 64];   // 32 KB
  const int tid  = threadIdx.x;
  const int w    = tid >> 6, lane = tid & 63;
  const int wu   = __builtin_amdgcn_readfirstlane(w);
  const int l32  = lane & 31, kh = lane >> 5;
  const int sup  = blockIdx.x / (32 * ncol);
  const int t    = blockIdx.x % (32 * ncol);
  const int row0 = (sup * 32 + (t & 31)) * 128, col0 = (t >> 5) * 128;
  const int wrow = (w >> 1) * 64,   wcol = (w & 1) * 64;

  // packed-B base for this wave: group g0 = col0/32 + (w&1)*2; +nt advances one group.
  const uint16_t* bw = Bpk + (size_t)((col0 >> 5) + (w & 1) * 2) * (NKB * 2048) + lane * 8;

  f32x16 acc[2][2] = {};

  // prologue: stage A(0) -> buf0
#pragma unroll
  for (int j = 0; j < 4; ++j) {
    int cid = j * 256 + tid;
    int r = cid >> 3, c = (cid & 7) ^ swz(r);
    async16(&Alds[0][(j * 256 + wu * 64) * 8],
            A + (size_t)(row0 + r) * 768 + c * 8);
  }

#pragma unroll 2
  for (int kb = 0; kb < NKB; ++kb) {
    const int cur = kb & 1;
    // B fragments: 8 contiguous-per-wave 16B loads (L2 hits)
    bf16x8 bfr[4][2];
#pragma unroll
    for (int ks = 0; ks < 4; ++ks)
#pragma unroll
      for (int nt = 0; nt < 2; ++nt)
        bfr[ks][nt] = *(const bf16x8*)(bw + (size_t)nt * (NKB * 2048) + (kb * 4 + ks) * 512);
    asm volatile("s_waitcnt lgkmcnt(0)" ::: "memory");   // WAR: prev ds_reads done
    asm volatile("s_waitcnt vmcnt(8)" ::: "memory");     // STAGE(kb) landed; B(kb) stays in flight
    __builtin_amdgcn_s_barrier();
    __builtin_amdgcn_sched_barrier(0);
    if (kb + 1 < NKB) {                                  // stage next tile into other buffer
#pragma unroll
      for (int j = 0; j < 4; ++j) {
        int cid = j * 256 + tid;
        int r = cid >> 3, c = (cid & 7) ^ swz(r);
        async16(&Alds[cur ^ 1][(j * 256 + wu * 64) * 8],
                A + (size_t)(row0 + r) * 768 + (kb + 1) * 64 + c * 8);
      }
    }
#pragma unroll
    for (int ks = 0; ks < 4; ++ks) {                     // 4 k-steps of 16
      bf16x8 af[2];
#pragma unroll
      for (int mt = 0; mt < 2; ++mt) {
        int r = wrow + mt * 32 + l32;
        int c = (ks * 2 + kh) ^ swz(r);
        af[mt] = *(const bf16x8*)&Alds[cur][r * 64 + c * 8];
      }
#pragma unroll
      for (int mt = 0; mt < 2; ++mt)
#pragma unroll
        for (int nt = 0; nt < 2; ++nt)
          acc[mt][nt] = MFMA32(af[mt], bfr[ks][nt], acc[mt][nt]);
    }
  }
  // epilogue: 32x32 C/D layout: col=lane&31, row=(reg&3)+8*(reg>>2)+4*(lane>>5)
#pragma unroll
  for (int nt = 0; nt < 2; ++nt) {
    int col = col0 + wcol + nt * 32 + l32;
    float bv = bias[col];
#pragma unroll
    for (int mt = 0; mt < 2; ++mt) {
#pragma unroll
      for (int rg = 0; rg < 16; ++rg) {
        int row = row0 + wrow + mt * 32 + (rg & 3) + 8 * (rg >> 2) + 4 * kh;
        float v = acc[mt][nt][rg] + bv;
        if (rowscale) v *= rowscale[row];
        C[(size_t)row * ldc + col] = f2bf(v);
      }
    }
  }
}

// ---------------- fused attention (unchanged) ----------------
__global__ __launch_bounds__(256) void k_attn(
    const uint16_t* __restrict__ QKV, const float* __restrict__ ts,
    const float* __restrict__ mask, uint16_t* __restrict__ Aout) {
  __shared__ uint16_t Klds[64 * 64];        // swizzled chunks, 8KB
  __shared__ uint16_t Vt[64 * 72];          // [d][k] padded, 9KB
  __shared__ uint16_t Plds[4][32 * 72];     // per-wave P tile, stride 72, 18KB
  __shared__ float tkl[SEQ];                // ts*c2, masked -> +3e38

  const int tid = threadIdx.x, w = tid >> 6, lane = tid & 63;
  const int wu = __builtin_amdgcn_readfirstlane(w);
  const int quad = lane >> 4, l16 = lane & 15;
  int b = blockIdx.x;
  int xcd = b & 7, i = b >> 3;
  int qt = i & 3;
  int hg = xcd * 96 + (i >> 2);             // 0..767
  int n = hg / NH, h = hg % NH;
  const int q0 = qt * 128 + w * 32;
  const size_t rowbase = (size_t)n * SEQ * NQKV;

  const float c1 = 0.125f * 1.44269504f;     // scale * log2(e)
  const float c2 = 1.44269504f / 300.0f;     // log2(e) / tau

  for (int l = tid; l < SEQ; l += 256) {
    float t = ts[n * SEQ + l] * c2;
    tkl[l] = (mask[n * SEQ + l] > 0.f) ? t : 3e38f;
  }

  // Q fragments (A-operand): A[m=lane&15][k=quad*8+j]
  bf16x8 qf[2][2];
  float tq[2][4];
#pragma unroll
  for (int qs = 0; qs < 2; ++qs) {
    int qr = q0 + qs * 16 + l16;
    const uint16_t* qp = QKV + rowbase + (size_t)qr * NQKV + h * DH;
#pragma unroll
    for (int dsp = 0; dsp < 2; ++dsp)
      qf[qs][dsp] = *(const bf16x8*)(qp + dsp * 32 + quad * 8);
#pragma unroll
    for (int rg = 0; rg < 4; ++rg)
      tq[qs][rg] = ts[n * SEQ + q0 + qs * 16 + quad * 4 + rg] * c2;
  }

  f32x4 accO[2][4] = {};
  f32x4 accL[2] = {};
  bf16x8 ones_b;
  {
    union { uint16_t u[8]; bf16x8 v; } t;
    uint16_t o = (l16 == 0) ? 0x3F80 : 0;   // bf16 1.0 in column 0 only
#pragma unroll
    for (int j = 0; j < 8; ++j) t.u[j] = o;
    ones_b = t.v;
  }
  uint16_t* Pw = &Plds[w][0];

  for (int k0 = 0; k0 < SEQ; k0 += 64) {
    __syncthreads();
    // stage K rows (row-major 64x64, swz-swizzled) via global_load_lds
#pragma unroll
    for (int j = 0; j < 2; ++j) {
      int cid = j * 256 + w * 64 + lane;      // 0..511
      int r = cid >> 3, cc = cid & 7, c = cc ^ swz(r);
      const uint16_t* g = QKV + rowbase + (size_t)(k0 + r) * NQKV + DM + h * DH + c * 8;
      async16(&Klds[(j * 256 + wu * 64) * 8], g);
    }
    // stage V transposed: Vt[d][k]
    {
      int r = tid & 63, db = (tid >> 6) * 16;
      const uint16_t* g = QKV + rowbase + (size_t)(k0 + r) * NQKV + 2 * DM + h * DH + db;
      union { uint4 v; uint16_t u[8]; } a0, a1;
      a0.v = *(const uint4*)g;
      a1.v = *(const uint4*)(g + 8);
#pragma unroll
      for (int j = 0; j < 8; ++j) Vt[(db + j) * 72 + r] = a0.u[j];
#pragma unroll
      for (int j = 0; j < 8; ++j) Vt[(db + 8 + j) * 72 + r] = a1.u[j];
    }
    __syncthreads();

#pragma unroll
    for (int kt = 0; kt < 2; ++kt) {
      // S = Q K^T over this 32-col k-tile; columns interleaved: n -> k = 2*(lane&15)+ksu
      f32x4 s[2][2] = {};
#pragma unroll
      for (int dsp = 0; dsp < 2; ++dsp) {
        bf16x8 kf[2];
#pragma unroll
        for (int ksu = 0; ksu < 2; ++ksu) {
          int r = kt * 32 + 2 * l16 + ksu;
          int c = (dsp * 4 + quad) ^ swz(r);
          kf[ksu] = *(const bf16x8*)&Klds[r * 64 + c * 8];
        }
#pragma unroll
        for (int qs = 0; qs < 2; ++qs)
#pragma unroll
          for (int ksu = 0; ksu < 2; ++ksu)
            s[qs][ksu] = MFMA16(qf[qs][dsp], kf[ksu], s[qs][ksu]);
      }
      // bias + exp + pack to bf16 pairs -> Plds[q][k] (natural k order)
      float tk0 = tkl[k0 + kt * 32 + 2 * l16];
      float tk1 = tkl[k0 + kt * 32 + 2 * l16 + 1];
#pragma unroll
      for (int qs = 0; qs < 2; ++qs) {
#pragma unroll
        for (int rg = 0; rg < 4; ++rg) {
          float d0 = fabsf(tq[qs][rg] - tk0);   // v_sub; abs/neg ride as fma modifiers
          float d1 = fabsf(tq[qs][rg] - tk1);
          float p0 = __builtin_amdgcn_exp2f(fmaf(s[qs][0][rg], c1, -d0));
          float p1 = __builtin_amdgcn_exp2f(fmaf(s[qs][1][rg], c1, -d1));
          uint32_t u = (__float_as_uint(p0) >> 16) | (__float_as_uint(p1) & 0xFFFF0000u);
          *(uint32_t*)(Pw + (qs * 16 + quad * 4 + rg) * 72 + kt * 32 + 2 * l16) = u;
        }
      }
      // PV (+ ones column for row-sums). Wave-private LDS: per-wave in-order, no barrier.
      bf16x8 vb[4];
#pragma unroll
      for (int dt = 0; dt < 4; ++dt)
        vb[dt] = *(const bf16x8*)&Vt[(dt * 16 + l16) * 72 + kt * 32 + quad * 8];
#pragma unroll
      for (int qs = 0; qs < 2; ++qs) {
        bf16x8 pa = *(const bf16x8*)(Pw + (qs * 16 + l16) * 72 + kt * 32 + quad * 8);
#pragma unroll
        for (int dt = 0; dt < 4; ++dt)
          accO[qs][dt] = MFMA16(pa, vb[dt], accO[qs][dt]);
        accL[qs] = MFMA16(pa, ones_b, accL[qs]);
      }
    }
  }
  // epilogue: O = accO / l ; l lives in column 0 (lane quad*16) of accL
#pragma unroll
  for (int qs = 0; qs < 2; ++qs) {
    float inv[4];
#pragma unroll
    for (int rg = 0; rg < 4; ++rg) {
      float lv = __shfl(accL[qs][rg], lane & 48, 64);
      inv[rg] = 1.0f / lv;
    }
#pragma unroll
    for (int dt = 0; dt < 4; ++dt) {
#pragma unroll
      for (int rg = 0; rg < 4; ++rg) {
        int qr = q0 + qs * 16 + quad * 4 + rg;
        float v = accO[qs][dt][rg] * inv[rg];
        Aout[(size_t)(n * SEQ + qr) * DM + h * DH + dt * 16 + l16] = f2bf(v);
      }
    }
  }
}

// ---------------- readout pooling (unchanged) ----------------
__global__ __launch_bounds__(256) void k_pool(
    const uint16_t* __restrict__ Out, const float* __restrict__ mask,
    const float* __restrict__ readout, float* __restrict__ dst) {
  __shared__ float rsl[64];
  __shared__ float ex[SEQ];
  __shared__ float red[4];
  __shared__ float part[8][64];
  int b = blockIdx.x;
  int n = b / NH, h = b % NH;
  int tid = threadIdx.x;
  if (tid < 64) rsl[tid] = readout[h * DH + tid];
  __syncthreads();

  float suml = 0.f;
  for (int l = tid; l < SEQ; l += 256) {
    const uint16_t* rowp = Out + (size_t)(n * SEQ + l) * DM + h * DH;
    float acc = 0.f;
#pragma unroll
    for (int c = 0; c < 8; ++c) {
      union { uint4 v; uint16_t u[8]; } t;
      t.v = *(const uint4*)(rowp + c * 8);
#pragma unroll
      for (int j = 0; j < 8; ++j)
        acc += __uint_as_float(((uint32_t)t.u[j]) << 16) * rsl[c * 8 + j];
    }
    float e = __builtin_amdgcn_exp2f(acc * (0.125f * 1.44269504f));
    e = (mask[n * SEQ + l] > 0.f) ? e : 0.f;
    ex[l] = e;
    suml += e;
  }
#pragma unroll
  for (int off = 32; off; off >>= 1) suml += __shfl_down(suml, off, 64);
  if ((tid & 63) == 0) red[tid >> 6] = suml;
  __syncthreads();
  float inv = 1.0f / (red[0] + red[1] + red[2] + red[3]);

  int d0 = (tid & 31) * 2, ch = tid >> 5;
  float a0 = 0.f, a1 = 0.f;
  for (int l = ch * 64; l < ch * 64 + 64; ++l) {
    uint32_t pv = *(const uint32_t*)(Out + (size_t)(n * SEQ + l) * DM + h * DH + d0);
    float e = ex[l];
    a0 = fmaf(__uint_as_float(pv << 16), e, a0);
    a1 = fmaf(__uint_as_float(pv & 0xFFFF0000u), e, a1);
  }
  part[ch][d0] = a0;
  part[ch][d0 + 1] = a1;
  __syncthreads();
  if (tid < 64) {
    float s = 0.f;
#pragma unroll
    for (int c = 0; c < 8; ++c) s += part[c][tid];
    dst[n * DM + h * DH + tid] = s * inv;
  }
}

// ---------------- launch ----------------
extern "C" void kernel_launch(void* const* d_in, const int* in_sizes, int n_in,
                              void* d_out, int out_size, void* d_ws, size_t ws_size,
                              hipStream_t stream) {
  const float* tokens  = (const float*)d_in[0];
  const float* ts      = (const float*)d_in[1];
  const float* mask    = (const float*)d_in[2];
  const float* Wq      = (const float*)d_in[3];
  const float* bq      = (const float*)d_in[4];
  const float* Wk      = (const float*)d_in[5];
  const float* bk      = (const float*)d_in[6];
  const float* Wv      = (const float*)d_in[7];
  const float* bv      = (const float*)d_in[8];
  const float* Wo      = (const float*)d_in[9];
  const float* bo      = (const float*)d_in[10];
  const float* readout = (const float*)d_in[11];

  char* ws = (char*)d_ws;
  uint16_t* X    = (uint16_t*)ws;                   // 50,331,648 B ; reused as attn_out
  uint16_t* Wqkv = (uint16_t*)(ws + 50331648);      //  3,538,944 B (packed)
  uint16_t* Wob  = (uint16_t*)(ws + 53870592);      //  1,179,648 B (packed)
  float*    bqkv = (float*)   (ws + 55050240);      //      9,216 B
  uint16_t* QKV  = (uint16_t*)(ws + 55059456);      // 150,994,944 B ; reused as Out
  uint16_t* attn = X;
  uint16_t* Outb = QKV;

  k_cvt<<<12288, 256, 0, stream>>>(tokens, Wq, Wk, Wv, Wo, bq, bk, bv, X, Wqkv, Wob, bqkv);
  k_gemm_bt<<<4608, 256, 0, stream>>>(X, Wqkv, bqkv, nullptr, QKV, NQKV, 18);
  k_attn<<<3072, 256, 0, stream>>>(QKV, ts, mask, attn);
  k_gemm_bt<<<1536, 256, 0, stream>>>(attn, Wob, bo, mask, Outb, DM, 6);
  k_pool<<<768, 256, 0, stream>>>(Outb, mask, readout, (float*)d_out);
}

// Round 3
// 525.157 us; speedup vs baseline: 1.0336x; 1.0116x over previous
//
#include <hip/hip_runtime.h>
#include <stdint.h>

#define AS1 __attribute__((address_space(1)))
#define AS3 __attribute__((address_space(3)))

typedef __bf16 bf16x8 __attribute__((ext_vector_type(8)));   // 4 VGPRs
typedef float  f32x4  __attribute__((ext_vector_type(4)));
typedef float  f32x16 __attribute__((ext_vector_type(16)));

#define MFMA16(a, b, c) __builtin_amdgcn_mfma_f32_16x16x32_bf16((a), (b), (c), 0, 0, 0)
#define MFMA32(a, b, c) __builtin_amdgcn_mfma_f32_32x32x16_bf16((a), (b), (c), 0, 0, 0)

// ---- constants for this problem ----
#define SEQ   512
#define NBAT  64
#define DM    768
#define NH    12
#define DH    64
#define NQKV  2304
#define NTOK  (NBAT * SEQ)   // 32768
#define NKB   12             // K=768 -> 12 K-tiles of 64

__device__ __forceinline__ uint16_t f2bf(float x) {          // fp32 -> bf16 RNE
  uint32_t u = __float_as_uint(x);
  return (uint16_t)((u + 0x7FFFu + ((u >> 16) & 1u)) >> 16);
}

__device__ __forceinline__ void async16(uint16_t* lds, const uint16_t* g) {
  // 16B global -> LDS direct (dest = wave-uniform base + lane*16)
  __builtin_amdgcn_global_load_lds((AS1 void*)(uintptr_t)(const void*)g,
                                   (AS3 void*)lds, 16, 0, 0);
}

// row->column XOR swizzle: conflict-free for the 32-row (l32/kh-split) MFMA
// fragment reads used below (measured 0 SQ_LDS_BANK_CONFLICT).
__device__ __forceinline__ int swz(int r) { return (r ^ (r >> 3)) & 7; }

// ---------------- merged converter + weight fragment-packing ----------------
// Packed layout: 16B chunk index ((g*NKB + kb)*4 + ks)*64 + lane holds
// B[row = g*32 + (lane&31)][k = kb*64 + ks*16 + (lane>>5)*8 .. +8) as bf16.
// A wave's per-(kb,ks) fragment load = 64 consecutive chunks = 1KB contiguous.
__global__ __launch_bounds__(256) void k_cvt(
    const float* __restrict__ tokens,
    const float* __restrict__ Wq, const float* __restrict__ Wk,
    const float* __restrict__ Wv, const float* __restrict__ Wo,
    const float* __restrict__ bq, const float* __restrict__ bk, const float* __restrict__ bv,
    uint16_t* __restrict__ X, uint16_t* __restrict__ Wqkv_pk, uint16_t* __restrict__ Wob_pk,
    float* __restrict__ bqkv) {
  int i = blockIdx.x * 256 + threadIdx.x;     // grid covers NTOK*DM/8 = 3,145,728
  {
    const float4* sp = (const float4*)tokens;
    float4 a = sp[2 * i], b = sp[2 * i + 1];
    union { uint16_t u[8]; uint4 v; } o;
    o.u[0] = f2bf(a.x); o.u[1] = f2bf(a.y); o.u[2] = f2bf(a.z); o.u[3] = f2bf(a.w);
    o.u[4] = f2bf(b.x); o.u[5] = f2bf(b.y); o.u[6] = f2bf(b.z); o.u[7] = f2bf(b.w);
    ((uint4*)X)[i] = o.v;
  }
  // Wqkv pack: 2304*768/8 = 221184 chunks
  if (i < 221184) {
    int lane = i & 63, ks = (i >> 6) & 3, kb = (i >> 8) % NKB, g = i / 3072;
    int row = g * 32 + (lane & 31);
    int k   = kb * 64 + ks * 16 + (lane >> 5) * 8;
    const float* src = (row < 768)  ? Wq + (size_t)row * 768 + k
                     : (row < 1536) ? Wk + (size_t)(row - 768) * 768 + k
                                    : Wv + (size_t)(row - 1536) * 768 + k;
    float4 a = *(const float4*)src, b = *(const float4*)(src + 4);
    union { uint16_t u[8]; uint4 v; } o;
    o.u[0] = f2bf(a.x); o.u[1] = f2bf(a.y); o.u[2] = f2bf(a.z); o.u[3] = f2bf(a.w);
    o.u[4] = f2bf(b.x); o.u[5] = f2bf(b.y); o.u[6] = f2bf(b.z); o.u[7] = f2bf(b.w);
    ((uint4*)Wqkv_pk)[i] = o.v;
  }
  // Wo pack: 768*768/8 = 73728 chunks
  if (i < 73728) {
    int lane = i & 63, ks = (i >> 6) & 3, kb = (i >> 8) % NKB, g = i / 3072;
    int row = g * 32 + (lane & 31);
    int k   = kb * 64 + ks * 16 + (lane >> 5) * 8;
    const float* src = Wo + (size_t)row * 768 + k;
    float4 a = *(const float4*)src, b = *(const float4*)(src + 4);
    union { uint16_t u[8]; uint4 v; } o;
    o.u[0] = f2bf(a.x); o.u[1] = f2bf(a.y); o.u[2] = f2bf(a.z); o.u[3] = f2bf(a.w);
    o.u[4] = f2bf(b.x); o.u[5] = f2bf(b.y); o.u[6] = f2bf(b.z); o.u[7] = f2bf(b.w);
    ((uint4*)Wob_pk)[i] = o.v;
  }
  if (i < 768) { bqkv[i] = bq[i]; bqkv[i + 768] = bk[i]; bqkv[i + 1536] = bv[i]; }
}

// ---------------- GEMM: C[M,N] = A[M,768] * B[N,768]^T + bias(col), optional *rowscale(row) ----------------
// R0 structure (128x128 tile, BK=64, 4 waves, single-buffered A in LDS,
// B fragment-packed -> registers from L2; proven 150us / 0 conflicts).
// R3 change: XCD-aware 2D-blocked traversal. grid = 8 XCDs x (rows_per_xcd x
// ncol); per XCD the 32 row-tiles split into 2 groups of 16 (A panel
// 16*128*768*2B = 3.1 MB < 4 MB XCD-L2), iterated row-fastest so the A panel
// stays L2-resident across all ncol column passes. Cuts A re-fetch from
// L3 (~3x over-read) to ~compulsory.
__global__ __launch_bounds__(256) void k_gemm_bt(
    const uint16_t* __restrict__ A, const uint16_t* __restrict__ Bpk,
    const float* __restrict__ bias, const float* __restrict__ rowscale,
    uint16_t* __restrict__ C, int ldc, int ncol) {
  __shared__ uint16_t Alds[128 * 64];   // 16 KB
  const int tid  = threadIdx.x;
  const int w    = tid >> 6, lane = tid & 63;
  const int wu   = __builtin_amdgcn_readfirstlane(w);
  const int l32  = lane & 31, kh = lane >> 5;
  // XCD-aware 2D-blocked block-id remap (bijective: gridDim % (8*16*ncol)==0)
  const int xcd  = blockIdx.x & 7, bi = blockIdx.x >> 3;
  const int span = 16 * ncol;                       // blocks per row-group
  const int rg   = bi / span, jj = bi - rg * span;
  const int rpx  = (int)(gridDim.x >> 3) / ncol;    // row-tiles per XCD (=32)
  const int rt   = xcd * rpx + rg * 16 + (jj & 15);
  const int row0 = rt * 128, col0 = (jj >> 4) * 128;
  const int wrow = (w >> 1) * 64,   wcol = (w & 1) * 64;

  // packed-B base for this wave: group g0 = col0/32 + (w&1)*2; +nt advances one group.
  const uint16_t* bw = Bpk + (size_t)((col0 >> 5) + (w & 1) * 2) * (NKB * 2048) + lane * 8;

  f32x16 acc[2][2] = {};
  for (int kb = 0; kb < NKB; ++kb) {
    // B fragments: 8 contiguous-per-wave 16B loads (L2 hits)
    bf16x8 bfr[4][2];
#pragma unroll
    for (int ks = 0; ks < 4; ++ks)
#pragma unroll
      for (int nt = 0; nt < 2; ++nt)
        bfr[ks][nt] = *(const bf16x8*)(bw + (size_t)nt * (NKB * 2048) + (kb * 4 + ks) * 512);
    __syncthreads();                              // prev iter's A-frag reads done
#pragma unroll
    for (int j = 0; j < 4; ++j) {                 // A: 1024 chunks
      int cid = j * 256 + w * 64 + lane;
      int r = cid >> 3, cc = cid & 7, c = cc ^ swz(r);
      async16(&Alds[(j * 256 + wu * 64) * 8],
              A + (size_t)(row0 + r) * 768 + kb * 64 + c * 8);
    }
    __syncthreads();                              // staging (and B loads) drained
#pragma unroll
    for (int ks = 0; ks < 4; ++ks) {              // 4 k-steps of 16
      bf16x8 af[2];
#pragma unroll
      for (int mt = 0; mt < 2; ++mt) {
        int r = wrow + mt * 32 + l32;
        int c = (ks * 2 + kh) ^ swz(r);
        af[mt] = *(const bf16x8*)&Alds[r * 64 + c * 8];
      }
#pragma unroll
      for (int mt = 0; mt < 2; ++mt)
#pragma unroll
        for (int nt = 0; nt < 2; ++nt)
          acc[mt][nt] = MFMA32(af[mt], bfr[ks][nt], acc[mt][nt]);
    }
  }
  // epilogue: 32x32 C/D layout: col=lane&31, row=(reg&3)+8*(reg>>2)+4*(lane>>5)
#pragma unroll
  for (int nt = 0; nt < 2; ++nt) {
    int col = col0 + wcol + nt * 32 + l32;
    float bv = bias[col];
#pragma unroll
    for (int mt = 0; mt < 2; ++mt) {
#pragma unroll
      for (int rg2 = 0; rg2 < 16; ++rg2) {
        int row = row0 + wrow + mt * 32 + (rg2 & 3) + 8 * (rg2 >> 2) + 4 * kh;
        float v = acc[mt][nt][rg2] + bv;
        if (rowscale) v *= rowscale[row];
        C[(size_t)row * ldc + col] = f2bf(v);
      }
    }
  }
}

// ---------------- fused attention ----------------
__global__ __launch_bounds__(256) void k_attn(
    const uint16_t* __restrict__ QKV, const float* __restrict__ ts,
    const float* __restrict__ mask, uint16_t* __restrict__ Aout) {
  __shared__ uint16_t Klds[64 * 64];        // swizzled chunks, 8KB
  __shared__ uint16_t Vt[64 * 72];          // [d][k] padded, 9KB
  __shared__ uint16_t Plds[4][32 * 72];     // per-wave P tile, stride 72, 18KB
  __shared__ float tkl[SEQ];                // ts*c2, masked -> +3e38

  const int tid = threadIdx.x, w = tid >> 6, lane = tid & 63;
  const int wu = __builtin_amdgcn_readfirstlane(w);
  const int quad = lane >> 4, l16 = lane & 15;
  int b = blockIdx.x;
  int xcd = b & 7, i = b >> 3;
  int qt = i & 3;
  int hg = xcd * 96 + (i >> 2);             // 0..767
  int n = hg / NH, h = hg % NH;
  const int q0 = qt * 128 + w * 32;
  const size_t rowbase = (size_t)n * SEQ * NQKV;

  const float c1 = 0.125f * 1.44269504f;     // scale * log2(e)
  const float c2 = 1.44269504f / 300.0f;     // log2(e) / tau

  for (int l = tid; l < SEQ; l += 256) {
    float t = ts[n * SEQ + l] * c2;
    tkl[l] = (mask[n * SEQ + l] > 0.f) ? t : 3e38f;
  }

  // Q fragments (A-operand): A[m=lane&15][k=quad*8+j]
  bf16x8 qf[2][2];
  float tq[2][4];
#pragma unroll
  for (int qs = 0; qs < 2; ++qs) {
    int qr = q0 + qs * 16 + l16;
    const uint16_t* qp = QKV + rowbase + (size_t)qr * NQKV + h * DH;
#pragma unroll
    for (int dsp = 0; dsp < 2; ++dsp)
      qf[qs][dsp] = *(const bf16x8*)(qp + dsp * 32 + quad * 8);
#pragma unroll
    for (int rg = 0; rg < 4; ++rg)
      tq[qs][rg] = ts[n * SEQ + q0 + qs * 16 + quad * 4 + rg] * c2;
  }

  f32x4 accO[2][4] = {};
  f32x4 accL[2] = {};
  bf16x8 ones_b;
  {
    union { uint16_t u[8]; bf16x8 v; } t;
    uint16_t o = (l16 == 0) ? 0x3F80 : 0;   // bf16 1.0 in column 0 only
#pragma unroll
    for (int j = 0; j < 8; ++j) t.u[j] = o;
    ones_b = t.v;
  }
  uint16_t* Pw = &Plds[w][0];

  for (int k0 = 0; k0 < SEQ; k0 += 64) {
    __syncthreads();
    // stage K rows (row-major 64x64, swz-swizzled) via global_load_lds
#pragma unroll
    for (int j = 0; j < 2; ++j) {
      int cid = j * 256 + w * 64 + lane;      // 0..511
      int r = cid >> 3, cc = cid & 7, c = cc ^ swz(r);
      const uint16_t* g = QKV + rowbase + (size_t)(k0 + r) * NQKV + DM + h * DH + c * 8;
      async16(&Klds[(j * 256 + wu * 64) * 8], g);
    }
    // stage V transposed: Vt[d][k]. R3: 4 rows x 4 d per thread ->
    // 4 ds_write_b64 (k-contiguous) instead of 32 scalar ds_write_b16.
    {
      int r0v = (tid & 15) * 4, db = (tid >> 4) * 4;   // tid>>4: 0..15 -> d 0..60
      const uint16_t* g = QKV + rowbase + (size_t)(k0 + r0v) * NQKV + 2 * DM + h * DH + db;
      union { uint16_t u[4]; uint2 d; } v0, v1, v2, v3;
      v0.d = *(const uint2*)g;
      v1.d = *(const uint2*)(g + NQKV);
      v2.d = *(const uint2*)(g + 2 * NQKV);
      v3.d = *(const uint2*)(g + 3 * NQKV);
#pragma unroll
      for (int j = 0; j < 4; ++j) {
        union { uint16_t u[4]; uint2 d; } wv;
        wv.u[0] = v0.u[j]; wv.u[1] = v1.u[j]; wv.u[2] = v2.u[j]; wv.u[3] = v3.u[j];
        *(uint2*)&Vt[(db + j) * 72 + r0v] = wv.d;
      }
    }
    __syncthreads();

#pragma unroll
    for (int kt = 0; kt < 2; ++kt) {
      // S = Q K^T over this 32-col k-tile; columns interleaved: n -> k = 2*(lane&15)+ksu
      f32x4 s[2][2] = {};
#pragma unroll
      for (int dsp = 0; dsp < 2; ++dsp) {
        bf16x8 kf[2];
#pragma unroll
        for (int ksu = 0; ksu < 2; ++ksu) {
          int r = kt * 32 + 2 * l16 + ksu;
          int c = (dsp * 4 + quad) ^ swz(r);
          kf[ksu] = *(const bf16x8*)&Klds[r * 64 + c * 8];
        }
#pragma unroll
        for (int qs = 0; qs < 2; ++qs)
#pragma unroll
          for (int ksu = 0; ksu < 2; ++ksu)
            s[qs][ksu] = MFMA16(qf[qs][dsp], kf[ksu], s[qs][ksu]);
      }
      // bias + exp + pack to bf16 pairs -> Plds[q][k] (natural k order)
      float tk0 = tkl[k0 + kt * 32 + 2 * l16];
      float tk1 = tkl[k0 + kt * 32 + 2 * l16 + 1];
#pragma unroll
      for (int qs = 0; qs < 2; ++qs) {
#pragma unroll
        for (int rg = 0; rg < 4; ++rg) {
          float d0 = fabsf(tq[qs][rg] - tk0);   // v_sub; abs/neg ride as fma modifiers
          float d1 = fabsf(tq[qs][rg] - tk1);
          float p0 = __builtin_amdgcn_exp2f(fmaf(s[qs][0][rg], c1, -d0));
          float p1 = __builtin_amdgcn_exp2f(fmaf(s[qs][1][rg], c1, -d1));
          uint32_t u = (__float_as_uint(p0) >> 16) | (__float_as_uint(p1) & 0xFFFF0000u);
          *(uint32_t*)(Pw + (qs * 16 + quad * 4 + rg) * 72 + kt * 32 + 2 * l16) = u;
        }
      }
      // PV (+ ones column for row-sums). Wave-private LDS: per-wave in-order, no barrier.
      bf16x8 vb[4];
#pragma unroll
      for (int dt = 0; dt < 4; ++dt)
        vb[dt] = *(const bf16x8*)&Vt[(dt * 16 + l16) * 72 + kt * 32 + quad * 8];
#pragma unroll
      for (int qs = 0; qs < 2; ++qs) {
        bf16x8 pa = *(const bf16x8*)(Pw + (qs * 16 + l16) * 72 + kt * 32 + quad * 8);
#pragma unroll
        for (int dt = 0; dt < 4; ++dt)
          accO[qs][dt] = MFMA16(pa, vb[dt], accO[qs][dt]);
        accL[qs] = MFMA16(pa, ones_b, accL[qs]);
      }
    }
  }
  // epilogue: O = accO / l ; l lives in column 0 (lane quad*16) of accL
#pragma unroll
  for (int qs = 0; qs < 2; ++qs) {
    float inv[4];
#pragma unroll
    for (int rg = 0; rg < 4; ++rg) {
      float lv = __shfl(accL[qs][rg], lane & 48, 64);
      inv[rg] = 1.0f / lv;
    }
#pragma unroll
    for (int dt = 0; dt < 4; ++dt) {
#pragma unroll
      for (int rg = 0; rg < 4; ++rg) {
        int qr = q0 + qs * 16 + quad * 4 + rg;
        float v = accO[qs][dt][rg] * inv[rg];
        Aout[(size_t)(n * SEQ + qr) * DM + h * DH + dt * 16 + l16] = f2bf(v);
      }
    }
  }
}

// ---------------- readout pooling (unchanged) ----------------
__global__ __launch_bounds__(256) void k_pool(
    const uint16_t* __restrict__ Out, const float* __restrict__ mask,
    const float* __restrict__ readout, float* __restrict__ dst) {
  __shared__ float rsl[64];
  __shared__ float ex[SEQ];
  __shared__ float red[4];
  __shared__ float part[8][64];
  int b = blockIdx.x;
  int n = b / NH, h = b % NH;
  int tid = threadIdx.x;
  if (tid < 64) rsl[tid] = readout[h * DH + tid];
  __syncthreads();

  float suml = 0.f;
  for (int l = tid; l < SEQ; l += 256) {
    const uint16_t* rowp = Out + (size_t)(n * SEQ + l) * DM + h * DH;
    float acc = 0.f;
#pragma unroll
    for (int c = 0; c < 8; ++c) {
      union { uint4 v; uint16_t u[8]; } t;
      t.v = *(const uint4*)(rowp + c * 8);
#pragma unroll
      for (int j = 0; j < 8; ++j)
        acc += __uint_as_float(((uint32_t)t.u[j]) << 16) * rsl[c * 8 + j];
    }
    float e = __builtin_amdgcn_exp2f(acc * (0.125f * 1.44269504f));
    e = (mask[n * SEQ + l] > 0.f) ? e : 0.f;
    ex[l] = e;
    suml += e;
  }
#pragma unroll
  for (int off = 32; off; off >>= 1) suml += __shfl_down(suml, off, 64);
  if ((tid & 63) == 0) red[tid >> 6] = suml;
  __syncthreads();
  float inv = 1.0f / (red[0] + red[1] + red[2] + red[3]);

  int d0 = (tid & 31) * 2, ch = tid >> 5;
  float a0 = 0.f, a1 = 0.f;
  for (int l = ch * 64; l < ch * 64 + 64; ++l) {
    uint32_t pv = *(const uint32_t*)(Out + (size_t)(n * SEQ + l) * DM + h * DH + d0);
    float e = ex[l];
    a0 = fmaf(__uint_as_float(pv << 16), e, a0);
    a1 = fmaf(__uint_as_float(pv & 0xFFFF0000u), e, a1);
  }
  part[ch][d0] = a0;
  part[ch][d0 + 1] = a1;
  __syncthreads();
  if (tid < 64) {
    float s = 0.f;
#pragma unroll
    for (int c = 0; c < 8; ++c) s += part[c][tid];
    dst[n * DM + h * DH + tid] = s * inv;
  }
}

// ---------------- launch ----------------
extern "C" void kernel_launch(void* const* d_in, const int* in_sizes, int n_in,
                              void* d_out, int out_size, void* d_ws, size_t ws_size,
                              hipStream_t stream) {
  const float* tokens  = (const float*)d_in[0];
  const float* ts      = (const float*)d_in[1];
  const float* mask    = (const float*)d_in[2];
  const float* Wq      = (const float*)d_in[3];
  const float* bq      = (const float*)d_in[4];
  const float* Wk      = (const float*)d_in[5];
  const float* bk      = (const float*)d_in[6];
  const float* Wv      = (const float*)d_in[7];
  const float* bv      = (const float*)d_in[8];
  const float* Wo      = (const float*)d_in[9];
  const float* bo      = (const float*)d_in[10];
  const float* readout = (const float*)d_in[11];

  char* ws = (char*)d_ws;
  uint16_t* X    = (uint16_t*)ws;                   // 50,331,648 B ; reused as attn_out
  uint16_t* Wqkv = (uint16_t*)(ws + 50331648);      //  3,538,944 B (packed)
  uint16_t* Wob  = (uint16_t*)(ws + 53870592);      //  1,179,648 B (packed)
  float*    bqkv = (float*)   (ws + 55050240);      //      9,216 B
  uint16_t* QKV  = (uint16_t*)(ws + 55059456);      // 150,994,944 B ; reused as Out
  uint16_t* attn = X;
  uint16_t* Outb = QKV;

  k_cvt<<<12288, 256, 0, stream>>>(tokens, Wq, Wk, Wv, Wo, bq, bk, bv, X, Wqkv, Wob, bqkv);
  k_gemm_bt<<<4608, 256, 0, stream>>>(X, Wqkv, bqkv, nullptr, QKV, NQKV, 18);
  k_attn<<<3072, 256, 0, stream>>>(QKV, ts, mask, attn);
  k_gemm_bt<<<1536, 256, 0, stream>>>(attn, Wob, bo, mask, Outb, DM, 6);
  k_pool<<<768, 256, 0, stream>>>(Outb, mask, readout, (float*)d_out);
}

// Round 7
// 488.235 us; speedup vs baseline: 1.1118x; 1.0756x over previous
//
#include <hip/hip_runtime.h>
#include <stdint.h>

#define AS1 __attribute__((address_space(1)))
#define AS3 __attribute__((address_space(3)))

typedef __bf16 bf16x8 __attribute__((ext_vector_type(8)));   // 4 VGPRs
typedef float  f32x4  __attribute__((ext_vector_type(4)));
typedef float  f32x16 __attribute__((ext_vector_type(16)));

#define MFMA16(a, b, c) __builtin_amdgcn_mfma_f32_16x16x32_bf16((a), (b), (c), 0, 0, 0)
#define MFMA32(a, b, c) __builtin_amdgcn_mfma_f32_32x32x16_bf16((a), (b), (c), 0, 0, 0)

// ---- constants for this problem ----
#define SEQ   512
#define NBAT  64
#define DM    768
#define NH    12
#define DH    64
#define NQKV  2304
#define NTOK  (NBAT * SEQ)   // 32768
#define NKB   12             // K=768 -> 12 K-tiles of 64

__device__ __forceinline__ uint16_t f2bf(float x) {          // fp32 -> bf16 RNE
  uint32_t u = __float_as_uint(x);
  return (uint16_t)((u + 0x7FFFu + ((u >> 16) & 1u)) >> 16);
}

__device__ __forceinline__ void async16(uint16_t* lds, const uint16_t* g) {
  // 16B global -> LDS direct (dest = wave-uniform base + lane*16)
  __builtin_amdgcn_global_load_lds((AS1 void*)(uintptr_t)(const void*)g,
                                   (AS3 void*)lds, 16, 0, 0);
}

// row->column XOR swizzle: conflict-free for the 32-row (l32/kh-split) MFMA
// fragment reads used below (measured 0 SQ_LDS_BANK_CONFLICT).
__device__ __forceinline__ int swz(int r) { return (r ^ (r >> 3)) & 7; }

// ---------------- merged converter + weight fragment-packing ----------------
// Packed layout: 16B chunk index ((g*NKB + kb)*4 + ks)*64 + lane holds
// B[row = g*32 + (lane&31)][k = kb*64 + ks*16 + (lane>>5)*8 .. +8) as bf16.
// A wave's per-(kb,ks) fragment load = 64 consecutive chunks = 1KB contiguous.
__global__ __launch_bounds__(256) void k_cvt(
    const float* __restrict__ tokens,
    const float* __restrict__ Wq, const float* __restrict__ Wk,
    const float* __restrict__ Wv, const float* __restrict__ Wo,
    const float* __restrict__ bq, const float* __restrict__ bk, const float* __restrict__ bv,
    uint16_t* __restrict__ X, uint16_t* __restrict__ Wqkv_pk, uint16_t* __restrict__ Wob_pk,
    float* __restrict__ bqkv) {
  int i = blockIdx.x * 256 + threadIdx.x;     // grid covers NTOK*DM/8 = 3,145,728
  {
    const float4* sp = (const float4*)tokens;
    float4 a = sp[2 * i], b = sp[2 * i + 1];
    union { uint16_t u[8]; uint4 v; } o;
    o.u[0] = f2bf(a.x); o.u[1] = f2bf(a.y); o.u[2] = f2bf(a.z); o.u[3] = f2bf(a.w);
    o.u[4] = f2bf(b.x); o.u[5] = f2bf(b.y); o.u[6] = f2bf(b.z); o.u[7] = f2bf(b.w);
    ((uint4*)X)[i] = o.v;
  }
  // Wqkv pack: 2304*768/8 = 221184 chunks
  if (i < 221184) {
    int lane = i & 63, ks = (i >> 6) & 3, kb = (i >> 8) % NKB, g = i / 3072;
    int row = g * 32 + (lane & 31);
    int k   = kb * 64 + ks * 16 + (lane >> 5) * 8;
    const float* src = (row < 768)  ? Wq + (size_t)row * 768 + k
                     : (row < 1536) ? Wk + (size_t)(row - 768) * 768 + k
                                    : Wv + (size_t)(row - 1536) * 768 + k;
    float4 a = *(const float4*)src, b = *(const float4*)(src + 4);
    union { uint16_t u[8]; uint4 v; } o;
    o.u[0] = f2bf(a.x); o.u[1] = f2bf(a.y); o.u[2] = f2bf(a.z); o.u[3] = f2bf(a.w);
    o.u[4] = f2bf(b.x); o.u[5] = f2bf(b.y); o.u[6] = f2bf(b.z); o.u[7] = f2bf(b.w);
    ((uint4*)Wqkv_pk)[i] = o.v;
  }
  // Wo pack: 768*768/8 = 73728 chunks
  if (i < 73728) {
    int lane = i & 63, ks = (i >> 6) & 3, kb = (i >> 8) % NKB, g = i / 3072;
    int row = g * 32 + (lane & 31);
    int k   = kb * 64 + ks * 16 + (lane >> 5) * 8;
    const float* src = Wo + (size_t)row * 768 + k;
    float4 a = *(const float4*)src, b = *(const float4*)(src + 4);
    union { uint16_t u[8]; uint4 v; } o;
    o.u[0] = f2bf(a.x); o.u[1] = f2bf(a.y); o.u[2] = f2bf(a.z); o.u[3] = f2bf(a.w);
    o.u[4] = f2bf(b.x); o.u[5] = f2bf(b.y); o.u[6] = f2bf(b.z); o.u[7] = f2bf(b.w);
    ((uint4*)Wob_pk)[i] = o.v;
  }
  if (i < 768) { bqkv[i] = bq[i]; bqkv[i + 768] = bk[i]; bqkv[i + 1536] = bv[i]; }
}

// ---------------- GEMM: C[M,N] = A[M,768] * B[N,768]^T + bias(col), optional *rowscale(row) ----------------
// R0 structure (best measured: ~150us, MfmaUtil 33%, 0 conflicts). Unchanged.
__global__ __launch_bounds__(256) void k_gemm_bt(
    const uint16_t* __restrict__ A, const uint16_t* __restrict__ Bpk,
    const float* __restrict__ bias, const float* __restrict__ rowscale,
    uint16_t* __restrict__ C, int ldc, int ncol) {
  __shared__ uint16_t Alds[128 * 64];   // 16 KB
  const int tid  = threadIdx.x;
  const int w    = tid >> 6, lane = tid & 63;
  const int wu   = __builtin_amdgcn_readfirstlane(w);
  const int l32  = lane & 31, kh = lane >> 5;
  const int sup  = blockIdx.x / (32 * ncol);
  const int t    = blockIdx.x % (32 * ncol);
  const int row0 = (sup * 32 + (t & 31)) * 128, col0 = (t >> 5) * 128;
  const int wrow = (w >> 1) * 64,   wcol = (w & 1) * 64;

  // packed-B base for this wave: group g0 = col0/32 + (w&1)*2; +nt advances one group.
  const uint16_t* bw = Bpk + (size_t)((col0 >> 5) + (w & 1) * 2) * (NKB * 2048) + lane * 8;

  f32x16 acc[2][2] = {};
  for (int kb = 0; kb < NKB; ++kb) {
    // B fragments: 8 contiguous-per-wave 16B loads (L2 hits)
    bf16x8 bfr[4][2];
#pragma unroll
    for (int ks = 0; ks < 4; ++ks)
#pragma unroll
      for (int nt = 0; nt < 2; ++nt)
        bfr[ks][nt] = *(const bf16x8*)(bw + (size_t)nt * (NKB * 2048) + (kb * 4 + ks) * 512);
    __syncthreads();                              // prev iter's A-frag reads done
#pragma unroll
    for (int j = 0; j < 4; ++j) {                 // A: 1024 chunks
      int cid = j * 256 + w * 64 + lane;
      int r = cid >> 3, cc = cid & 7, c = cc ^ swz(r);
      async16(&Alds[(j * 256 + wu * 64) * 8],
              A + (size_t)(row0 + r) * 768 + kb * 64 + c * 8);
    }
    __syncthreads();                              // staging (and B loads) drained
#pragma unroll
    for (int ks = 0; ks < 4; ++ks) {              // 4 k-steps of 16
      bf16x8 af[2];
#pragma unroll
      for (int mt = 0; mt < 2; ++mt) {
        int r = wrow + mt * 32 + l32;
        int c = (ks * 2 + kh) ^ swz(r);
        af[mt] = *(const bf16x8*)&Alds[r * 64 + c * 8];
      }
#pragma unroll
      for (int mt = 0; mt < 2; ++mt)
#pragma unroll
        for (int nt = 0; nt < 2; ++nt)
          acc[mt][nt] = MFMA32(af[mt], bfr[ks][nt], acc[mt][nt]);
    }
  }
  // epilogue: 32x32 C/D layout: col=lane&31, row=(reg&3)+8*(reg>>2)+4*(lane>>5)
#pragma unroll
  for (int nt = 0; nt < 2; ++nt) {
    int col = col0 + wcol + nt * 32 + l32;
    float bv = bias[col];
#pragma unroll
    for (int mt = 0; mt < 2; ++mt) {
#pragma unroll
      for (int rg = 0; rg < 16; ++rg) {
        int row = row0 + wrow + mt * 32 + (rg & 3) + 8 * (rg >> 2) + 4 * kh;
        float v = acc[mt][nt][rg] + bv;
        if (rowscale) v *= rowscale[row];
        C[(size_t)row * ldc + col] = f2bf(v);
      }
    }
  }
}

// ---------------- fused attention: R6 structure, V-address bug fixed (+vdb) ----------------
// Per tile t: V(t+1) global->reg loads issue BEFORE compute(t) (latency under
// compute); after the post-compute barrier: Vt write (from regs) + K(t+1)
// global_load_lds into the single Klds; second barrier drains. Same 2
// barriers/tile as R0. Plds kt-indexed (cross-kt disjoint) + explicit fences
// pinning P-write->PV-read->next-write order. T5 setprio around MFMA clusters.
// R4-R6 BUG (now fixed): V global loads omitted the per-thread d-offset vdb,
// filling Vt rows 16..63 with copies of d=0..15 (deterministic absmax 0.24).
__global__ __launch_bounds__(256) void k_attn(
    const uint16_t* __restrict__ QKV, const float* __restrict__ ts,
    const float* __restrict__ mask, uint16_t* __restrict__ Aout) {
  __shared__ uint16_t Klds[64 * 64];          // swizzled chunks, 8KB
  __shared__ uint16_t Vt[64 * 72];            // [d][k] padded, 9KB
  __shared__ uint16_t Plds[4][2 * 32 * 40];   // per-wave, kt-indexed, 20KB
  __shared__ float tkl[SEQ];                  // ts*c2, masked -> +3e38

  const int tid = threadIdx.x, w = tid >> 6, lane = tid & 63;
  const int wu = __builtin_amdgcn_readfirstlane(w);
  const int quad = lane >> 4, l16 = lane & 15;
  int b = blockIdx.x;
  int xcd = b & 7, i = b >> 3;
  int qt = i & 3;
  int hg = xcd * 96 + (i >> 2);             // 0..767
  int n = hg / NH, h = hg % NH;
  const int q0 = qt * 128 + w * 32;
  const size_t rowbase = (size_t)n * SEQ * NQKV;

  const float c1 = 0.125f * 1.44269504f;     // scale * log2(e)
  const float c2 = 1.44269504f / 300.0f;     // log2(e) / tau

  for (int l = tid; l < SEQ; l += 256) {
    float t = ts[n * SEQ + l] * c2;
    tkl[l] = (mask[n * SEQ + l] > 0.f) ? t : 3e38f;
  }

  // Q fragments (A-operand): A[m=lane&15][k=quad*8+j]
  bf16x8 qf[2][2];
  float tq[2][4];
#pragma unroll
  for (int qs = 0; qs < 2; ++qs) {
    int qr = q0 + qs * 16 + l16;
    const uint16_t* qp = QKV + rowbase + (size_t)qr * NQKV + h * DH;
#pragma unroll
    for (int dsp = 0; dsp < 2; ++dsp)
      qf[qs][dsp] = *(const bf16x8*)(qp + dsp * 32 + quad * 8);
#pragma unroll
    for (int rg = 0; rg < 4; ++rg)
      tq[qs][rg] = ts[n * SEQ + q0 + qs * 16 + quad * 4 + rg] * c2;
  }

  f32x4 accO[2][4] = {};
  f32x4 accL[2] = {};
  bf16x8 ones_b;
  {
    union { uint16_t u[8]; bf16x8 v; } t;
    uint16_t o = (l16 == 0) ? 0x3F80 : 0;   // bf16 1.0 in column 0 only
#pragma unroll
    for (int j = 0; j < 8; ++j) t.u[j] = o;
    ones_b = t.v;
  }
  uint16_t* Pw = &Plds[w][0];

  const uint16_t* Kbase = QKV + rowbase + DM + h * DH;
  const uint16_t* Vbase = QKV + rowbase + 2 * DM + h * DH;
  const int vr = tid & 63, vdb = (tid >> 6) * 16;
  uint4 vreg0, vreg1;

  // prologue: stage tile 0 (K via gload_lds, V via regs)
#pragma unroll
  for (int j = 0; j < 2; ++j) {
    int cid = j * 256 + w * 64 + lane;
    int r = cid >> 3, cc = cid & 7, c = cc ^ swz(r);
    async16(&Klds[(j * 256 + wu * 64) * 8], Kbase + (size_t)r * NQKV + c * 8);
  }
  vreg0 = *(const uint4*)(Vbase + (size_t)vr * NQKV + vdb);
  vreg1 = *(const uint4*)(Vbase + (size_t)vr * NQKV + vdb + 8);
  __syncthreads();                           // vmcnt drained: K0 in LDS, V0 in regs
  {
    union { uint4 v; uint16_t u[8]; } a0, a1;
    a0.v = vreg0; a1.v = vreg1;
#pragma unroll
    for (int j = 0; j < 8; ++j) Vt[(vdb + j) * 72 + vr] = a0.u[j];
#pragma unroll
    for (int j = 0; j < 8; ++j) Vt[(vdb + 8 + j) * 72 + vr] = a1.u[j];
  }
  __syncthreads();                           // tile 0 ready

  for (int it = 0; it < 8; ++it) {
    const int k0 = it * 64;
    // V(t+1) global->reg, issued before compute so HBM latency hides under it
    if (it < 7) {
      vreg0 = *(const uint4*)(Vbase + (size_t)(k0 + 64 + vr) * NQKV + vdb);
      vreg1 = *(const uint4*)(Vbase + (size_t)(k0 + 64 + vr) * NQKV + vdb + 8);
    }

#pragma unroll
    for (int kt = 0; kt < 2; ++kt) {
      uint16_t* Pk = Pw + kt * 1280;         // kt-indexed: cross-kt disjoint
      // S = Q K^T over this 32-col k-tile; columns interleaved: n -> k = 2*(lane&15)+ksu
      f32x4 s[2][2] = {};
      __builtin_amdgcn_s_setprio(1);
#pragma unroll
      for (int dsp = 0; dsp < 2; ++dsp) {
        bf16x8 kf[2];
#pragma unroll
        for (int ksu = 0; ksu < 2; ++ksu) {
          int r = kt * 32 + 2 * l16 + ksu;
          int c = (dsp * 4 + quad) ^ swz(r);
          kf[ksu] = *(const bf16x8*)&Klds[r * 64 + c * 8];
        }
#pragma unroll
        for (int qs = 0; qs < 2; ++qs)
#pragma unroll
          for (int ksu = 0; ksu < 2; ++ksu)
            s[qs][ksu] = MFMA16(qf[qs][dsp], kf[ksu], s[qs][ksu]);
      }
      __builtin_amdgcn_s_setprio(0);
      // bias + exp + pack to bf16 pairs -> Pk[q][k] (natural k order)
      float tk0 = tkl[k0 + kt * 32 + 2 * l16];
      float tk1 = tkl[k0 + kt * 32 + 2 * l16 + 1];
#pragma unroll
      for (int qs = 0; qs < 2; ++qs) {
#pragma unroll
        for (int rg = 0; rg < 4; ++rg) {
          float d0 = fabsf(tq[qs][rg] - tk0);   // v_sub; abs/neg ride as fma modifiers
          float d1 = fabsf(tq[qs][rg] - tk1);
          float p0 = __builtin_amdgcn_exp2f(fmaf(s[qs][0][rg], c1, -d0));
          float p1 = __builtin_amdgcn_exp2f(fmaf(s[qs][1][rg], c1, -d1));
          uint32_t u = (__float_as_uint(p0) >> 16) | (__float_as_uint(p1) & 0xFFFF0000u);
          *(uint32_t*)(Pk + (qs * 16 + quad * 4 + rg) * 40 + 2 * l16) = u;
        }
      }
      // fence: P-writes must precede cross-lane PV reads (compiler can't see alias)
      asm volatile("" ::: "memory");
      __builtin_amdgcn_sched_barrier(0);
      // PV (+ ones column for row-sums). Wave-private LDS, HW DS pipe is in-order.
      bf16x8 vb[4];
#pragma unroll
      for (int dt = 0; dt < 4; ++dt)
        vb[dt] = *(const bf16x8*)&Vt[(dt * 16 + l16) * 72 + kt * 32 + quad * 8];
      __builtin_amdgcn_s_setprio(1);
#pragma unroll
      for (int qs = 0; qs < 2; ++qs) {
        bf16x8 pa = *(const bf16x8*)(Pk + (qs * 16 + l16) * 40 + quad * 8);
#pragma unroll
        for (int dt = 0; dt < 4; ++dt)
          accO[qs][dt] = MFMA16(pa, vb[dt], accO[qs][dt]);
        accL[qs] = MFMA16(pa, ones_b, accL[qs]);
      }
      __builtin_amdgcn_s_setprio(0);
      // fence: PV reads must precede any later writes to Plds
      asm volatile("" ::: "memory");
      __builtin_amdgcn_sched_barrier(0);
    }

    __syncthreads();                         // all reads of Klds/Vt done; vmcnt drained
    if (it < 7) {
      {                                      // V(t+1) reg -> LDS transpose
        union { uint4 v; uint16_t u[8]; } a0, a1;
        a0.v = vreg0; a1.v = vreg1;
#pragma unroll
        for (int j = 0; j < 8; ++j) Vt[(vdb + j) * 72 + vr] = a0.u[j];
#pragma unroll
        for (int j = 0; j < 8; ++j) Vt[(vdb + 8 + j) * 72 + vr] = a1.u[j];
      }
#pragma unroll
      for (int j = 0; j < 2; ++j) {          // K(t+1) async into Klds
        int cid = j * 256 + w * 64 + lane;
        int r = cid >> 3, cc = cid & 7, c = cc ^ swz(r);
        async16(&Klds[(j * 256 + wu * 64) * 8],
                Kbase + (size_t)(k0 + 64 + r) * NQKV + c * 8);
      }
    }
    __syncthreads();                         // tile it+1 ready
  }
  // epilogue: O = accO / l ; l lives in column 0 (lane quad*16) of accL
#pragma unroll
  for (int qs = 0; qs < 2; ++qs) {
    float inv[4];
#pragma unroll
    for (int rg = 0; rg < 4; ++rg) {
      float lv = __shfl(accL[qs][rg], lane & 48, 64);
      inv[rg] = 1.0f / lv;
    }
#pragma unroll
    for (int dt = 0; dt < 4; ++dt) {
#pragma unroll
      for (int rg = 0; rg < 4; ++rg) {
        int qr = q0 + qs * 16 + quad * 4 + rg;
        float v = accO[qs][dt][rg] * inv[rg];
        Aout[(size_t)(n * SEQ + qr) * DM + h * DH + dt * 16 + l16] = f2bf(v);
      }
    }
  }
}

// ---------------- readout pooling (unchanged) ----------------
__global__ __launch_bounds__(256) void k_pool(
    const uint16_t* __restrict__ Out, const float* __restrict__ mask,
    const float* __restrict__ readout, float* __restrict__ dst) {
  __shared__ float rsl[64];
  __shared__ float ex[SEQ];
  __shared__ float red[4];
  __shared__ float part[8][64];
  int b = blockIdx.x;
  int n = b / NH, h = b % NH;
  int tid = threadIdx.x;
  if (tid < 64) rsl[tid] = readout[h * DH + tid];
  __syncthreads();

  float suml = 0.f;
  for (int l = tid; l < SEQ; l += 256) {
    const uint16_t* rowp = Out + (size_t)(n * SEQ + l) * DM + h * DH;
    float acc = 0.f;
#pragma unroll
    for (int c = 0; c < 8; ++c) {
      union { uint4 v; uint16_t u[8]; } t;
      t.v = *(const uint4*)(rowp + c * 8);
#pragma unroll
      for (int j = 0; j < 8; ++j)
        acc += __uint_as_float(((uint32_t)t.u[j]) << 16) * rsl[c * 8 + j];
    }
    float e = __builtin_amdgcn_exp2f(acc * (0.125f * 1.44269504f));
    e = (mask[n * SEQ + l] > 0.f) ? e : 0.f;
    ex[l] = e;
    suml += e;
  }
#pragma unroll
  for (int off = 32; off; off >>= 1) suml += __shfl_down(suml, off, 64);
  if ((tid & 63) == 0) red[tid >> 6] = suml;
  __syncthreads();
  float inv = 1.0f / (red[0] + red[1] + red[2] + red[3]);

  int d0 = (tid & 31) * 2, ch = tid >> 5;
  float a0 = 0.f, a1 = 0.f;
  for (int l = ch * 64; l < ch * 64 + 64; ++l) {
    uint32_t pv = *(const uint32_t*)(Out + (size_t)(n * SEQ + l) * DM + h * DH + d0);
    float e = ex[l];
    a0 = fmaf(__uint_as_float(pv << 16), e, a0);
    a1 = fmaf(__uint_as_float(pv & 0xFFFF0000u), e, a1);
  }
  part[ch][d0] = a0;
  part[ch][d0 + 1] = a1;
  __syncthreads();
  if (tid < 64) {
    float s = 0.f;
#pragma unroll
    for (int c = 0; c < 8; ++c) s += part[c][tid];
    dst[n * DM + h * DH + tid] = s * inv;
  }
}

// ---------------- launch ----------------
extern "C" void kernel_launch(void* const* d_in, const int* in_sizes, int n_in,
                              void* d_out, int out_size, void* d_ws, size_t ws_size,
                              hipStream_t stream) {
  const float* tokens  = (const float*)d_in[0];
  const float* ts      = (const float*)d_in[1];
  const float* mask    = (const float*)d_in[2];
  const float* Wq      = (const float*)d_in[3];
  const float* bq      = (const float*)d_in[4];
  const float* Wk      = (const float*)d_in[5];
  const float* bk      = (const float*)d_in[6];
  const float* Wv      = (const float*)d_in[7];
  const float* bv      = (const float*)d_in[8];
  const float* Wo      = (const float*)d_in[9];
  const float* bo      = (const float*)d_in[10];
  const float* readout = (const float*)d_in[11];

  char* ws = (char*)d_ws;
  uint16_t* X    = (uint16_t*)ws;                   // 50,331,648 B ; reused as attn_out
  uint16_t* Wqkv = (uint16_t*)(ws + 50331648);      //  3,538,944 B (packed)
  uint16_t* Wob  = (uint16_t*)(ws + 53870592);      //  1,179,648 B (packed)
  float*    bqkv = (float*)   (ws + 55050240);      //      9,216 B
  uint16_t* QKV  = (uint16_t*)(ws + 55059456);      // 150,994,944 B ; reused as Out
  uint16_t* attn = X;
  uint16_t* Outb = QKV;

  k_cvt<<<12288, 256, 0, stream>>>(tokens, Wq, Wk, Wv, Wo, bq, bk, bv, X, Wqkv, Wob, bqkv);
  k_gemm_bt<<<4608, 256, 0, stream>>>(X, Wqkv, bqkv, nullptr, QKV, NQKV, 18);
  k_attn<<<3072, 256, 0, stream>>>(QKV, ts, mask, attn);
  k_gemm_bt<<<1536, 256, 0, stream>>>(attn, Wob, bo, mask, Outb, DM, 6);
  k_pool<<<768, 256, 0, stream>>>(Outb, mask, readout, (float*)d_out);
}

// Round 8
// 481.611 us; speedup vs baseline: 1.1271x; 1.0138x over previous
//
#include <hip/hip_runtime.h>
#include <stdint.h>

#define AS1 __attribute__((address_space(1)))
#define AS3 __attribute__((address_space(3)))

typedef __bf16 bf16x8 __attribute__((ext_vector_type(8)));   // 4 VGPRs
typedef float  f32x4  __attribute__((ext_vector_type(4)));
typedef float  f32x16 __attribute__((ext_vector_type(16)));

#define MFMA16(a, b, c) __builtin_amdgcn_mfma_f32_16x16x32_bf16((a), (b), (c), 0, 0, 0)
#define MFMA32(a, b, c) __builtin_amdgcn_mfma_f32_32x32x16_bf16((a), (b), (c), 0, 0, 0)

// ---- constants for this problem ----
#define SEQ   512
#define NBAT  64
#define DM    768
#define NH    12
#define DH    64
#define NQKV  2304
#define NTOK  (NBAT * SEQ)   // 32768
#define NKB   12             // K=768 -> 12 K-tiles of 64

__device__ __forceinline__ uint16_t f2bf(float x) {          // fp32 -> bf16 RNE
  uint32_t u = __float_as_uint(x);
  return (uint16_t)((u + 0x7FFFu + ((u >> 16) & 1u)) >> 16);
}

__device__ __forceinline__ void async16(uint16_t* lds, const uint16_t* g) {
  // 16B global -> LDS direct (dest = wave-uniform base + lane*16)
  __builtin_amdgcn_global_load_lds((AS1 void*)(uintptr_t)(const void*)g,
                                   (AS3 void*)lds, 16, 0, 0);
}

// row->column XOR swizzle: conflict-free for the 32-row (l32/kh-split) MFMA
// fragment reads used below (measured 0 SQ_LDS_BANK_CONFLICT).
__device__ __forceinline__ int swz(int r) { return (r ^ (r >> 3)) & 7; }

// ---------------- merged converter + weight fragment-packing ----------------
// Packed layout: 16B chunk index ((g*NKB + kb)*4 + ks)*64 + lane holds
// B[row = g*32 + (lane&31)][k = kb*64 + ks*16 + (lane>>5)*8 .. +8) as bf16.
// A wave's per-(kb,ks) fragment load = 64 consecutive chunks = 1KB contiguous.
__global__ __launch_bounds__(256) void k_cvt(
    const float* __restrict__ tokens,
    const float* __restrict__ Wq, const float* __restrict__ Wk,
    const float* __restrict__ Wv, const float* __restrict__ Wo,
    const float* __restrict__ bq, const float* __restrict__ bk, const float* __restrict__ bv,
    uint16_t* __restrict__ X, uint16_t* __restrict__ Wqkv_pk, uint16_t* __restrict__ Wob_pk,
    float* __restrict__ bqkv) {
  int i = blockIdx.x * 256 + threadIdx.x;     // grid covers NTOK*DM/8 = 3,145,728
  {
    const float4* sp = (const float4*)tokens;
    float4 a = sp[2 * i], b = sp[2 * i + 1];
    union { uint16_t u[8]; uint4 v; } o;
    o.u[0] = f2bf(a.x); o.u[1] = f2bf(a.y); o.u[2] = f2bf(a.z); o.u[3] = f2bf(a.w);
    o.u[4] = f2bf(b.x); o.u[5] = f2bf(b.y); o.u[6] = f2bf(b.z); o.u[7] = f2bf(b.w);
    ((uint4*)X)[i] = o.v;
  }
  // Wqkv pack: 2304*768/8 = 221184 chunks
  if (i < 221184) {
    int lane = i & 63, ks = (i >> 6) & 3, kb = (i >> 8) % NKB, g = i / 3072;
    int row = g * 32 + (lane & 31);
    int k   = kb * 64 + ks * 16 + (lane >> 5) * 8;
    const float* src = (row < 768)  ? Wq + (size_t)row * 768 + k
                     : (row < 1536) ? Wk + (size_t)(row - 768) * 768 + k
                                    : Wv + (size_t)(row - 1536) * 768 + k;
    float4 a = *(const float4*)src, b = *(const float4*)(src + 4);
    union { uint16_t u[8]; uint4 v; } o;
    o.u[0] = f2bf(a.x); o.u[1] = f2bf(a.y); o.u[2] = f2bf(a.z); o.u[3] = f2bf(a.w);
    o.u[4] = f2bf(b.x); o.u[5] = f2bf(b.y); o.u[6] = f2bf(b.z); o.u[7] = f2bf(b.w);
    ((uint4*)Wqkv_pk)[i] = o.v;
  }
  // Wo pack: 768*768/8 = 73728 chunks
  if (i < 73728) {
    int lane = i & 63, ks = (i >> 6) & 3, kb = (i >> 8) % NKB, g = i / 3072;
    int row = g * 32 + (lane & 31);
    int k   = kb * 64 + ks * 16 + (lane >> 5) * 8;
    const float* src = Wo + (size_t)row * 768 + k;
    float4 a = *(const float4*)src, b = *(const float4*)(src + 4);
    union { uint16_t u[8]; uint4 v; } o;
    o.u[0] = f2bf(a.x); o.u[1] = f2bf(a.y); o.u[2] = f2bf(a.z); o.u[3] = f2bf(a.w);
    o.u[4] = f2bf(b.x); o.u[5] = f2bf(b.y); o.u[6] = f2bf(b.z); o.u[7] = f2bf(b.w);
    ((uint4*)Wob_pk)[i] = o.v;
  }
  if (i < 768) { bqkv[i] = bq[i]; bqkv[i + 768] = bk[i]; bqkv[i + 1536] = bv[i]; }
}

// ---------------- GEMM: C[M,N] = A[M,768] * B[N,768]^T + bias(col), optional *rowscale(row) ----------------
// R0 body + R8 occupancy fix. Analysis: per-SIMD VGPR pool = 512 (m69);
// R0's ~84 arch VGPR + 64 acc AGPR ~= 148/wave -> 3 waves/SIMD (30% occ
// measured) -> drains (FETCH 148MB vs 53MB compulsory -> A staging is
// L3/HBM-latency) can't be covered -> MfmaUtil 34%. Fix: cap unified regs
// at 128 via __launch_bounds__(256,4) -> 4 waves/SIMD, and move B-fragment
// loads inside the ks-loop (8 live regs instead of 32) so the cap doesn't
// spill. B is L2-resident; its ~200cyc latency hides under other waves.
__global__ __launch_bounds__(256, 4) void k_gemm_bt(
    const uint16_t* __restrict__ A, const uint16_t* __restrict__ Bpk,
    const float* __restrict__ bias, const float* __restrict__ rowscale,
    uint16_t* __restrict__ C, int ldc, int ncol) {
  __shared__ uint16_t Alds[128 * 64];   // 16 KB
  const int tid  = threadIdx.x;
  const int w    = tid >> 6, lane = tid & 63;
  const int wu   = __builtin_amdgcn_readfirstlane(w);
  const int l32  = lane & 31, kh = lane >> 5;
  const int sup  = blockIdx.x / (32 * ncol);
  const int t    = blockIdx.x % (32 * ncol);
  const int row0 = (sup * 32 + (t & 31)) * 128, col0 = (t >> 5) * 128;
  const int wrow = (w >> 1) * 64,   wcol = (w & 1) * 64;

  // packed-B base for this wave: group g0 = col0/32 + (w&1)*2; +nt advances one group.
  const uint16_t* bw = Bpk + (size_t)((col0 >> 5) + (w & 1) * 2) * (NKB * 2048) + lane * 8;

  f32x16 acc[2][2] = {};
  for (int kb = 0; kb < NKB; ++kb) {
    __syncthreads();                              // prev iter's A-frag reads done
#pragma unroll
    for (int j = 0; j < 4; ++j) {                 // A: 1024 chunks
      int cid = j * 256 + w * 64 + lane;
      int r = cid >> 3, cc = cid & 7, c = cc ^ swz(r);
      async16(&Alds[(j * 256 + wu * 64) * 8],
              A + (size_t)(row0 + r) * 768 + kb * 64 + c * 8);
    }
    __syncthreads();                              // staging drained
#pragma unroll
    for (int ks = 0; ks < 4; ++ks) {              // 4 k-steps of 16
      // B fragments for this k-step: 2 contiguous 16B loads (L2 hits)
      bf16x8 bfr[2];
#pragma unroll
      for (int nt = 0; nt < 2; ++nt)
        bfr[nt] = *(const bf16x8*)(bw + (size_t)nt * (NKB * 2048) + (kb * 4 + ks) * 512);
      bf16x8 af[2];
#pragma unroll
      for (int mt = 0; mt < 2; ++mt) {
        int r = wrow + mt * 32 + l32;
        int c = (ks * 2 + kh) ^ swz(r);
        af[mt] = *(const bf16x8*)&Alds[r * 64 + c * 8];
      }
#pragma unroll
      for (int mt = 0; mt < 2; ++mt)
#pragma unroll
        for (int nt = 0; nt < 2; ++nt)
          acc[mt][nt] = MFMA32(af[mt], bfr[nt], acc[mt][nt]);
    }
  }
  // epilogue: 32x32 C/D layout: col=lane&31, row=(reg&3)+8*(reg>>2)+4*(lane>>5)
#pragma unroll
  for (int nt = 0; nt < 2; ++nt) {
    int col = col0 + wcol + nt * 32 + l32;
    float bv = bias[col];
#pragma unroll
    for (int mt = 0; mt < 2; ++mt) {
#pragma unroll
      for (int rg = 0; rg < 16; ++rg) {
        int row = row0 + wrow + mt * 32 + (rg & 3) + 8 * (rg >> 2) + 4 * kh;
        float v = acc[mt][nt][rg] + bv;
        if (rowscale) v *= rowscale[row];
        C[(size_t)row * ldc + col] = f2bf(v);
      }
    }
  }
}

// ---------------- fused attention (R7-proven, unchanged) ----------------
__global__ __launch_bounds__(256) void k_attn(
    const uint16_t* __restrict__ QKV, const float* __restrict__ ts,
    const float* __restrict__ mask, uint16_t* __restrict__ Aout) {
  __shared__ uint16_t Klds[64 * 64];          // swizzled chunks, 8KB
  __shared__ uint16_t Vt[64 * 72];            // [d][k] padded, 9KB
  __shared__ uint16_t Plds[4][2 * 32 * 40];   // per-wave, kt-indexed, 20KB
  __shared__ float tkl[SEQ];                  // ts*c2, masked -> +3e38

  const int tid = threadIdx.x, w = tid >> 6, lane = tid & 63;
  const int wu = __builtin_amdgcn_readfirstlane(w);
  const int quad = lane >> 4, l16 = lane & 15;
  int b = blockIdx.x;
  int xcd = b & 7, i = b >> 3;
  int qt = i & 3;
  int hg = xcd * 96 + (i >> 2);             // 0..767
  int n = hg / NH, h = hg % NH;
  const int q0 = qt * 128 + w * 32;
  const size_t rowbase = (size_t)n * SEQ * NQKV;

  const float c1 = 0.125f * 1.44269504f;     // scale * log2(e)
  const float c2 = 1.44269504f / 300.0f;     // log2(e) / tau

  for (int l = tid; l < SEQ; l += 256) {
    float t = ts[n * SEQ + l] * c2;
    tkl[l] = (mask[n * SEQ + l] > 0.f) ? t : 3e38f;
  }

  // Q fragments (A-operand): A[m=lane&15][k=quad*8+j]
  bf16x8 qf[2][2];
  float tq[2][4];
#pragma unroll
  for (int qs = 0; qs < 2; ++qs) {
    int qr = q0 + qs * 16 + l16;
    const uint16_t* qp = QKV + rowbase + (size_t)qr * NQKV + h * DH;
#pragma unroll
    for (int dsp = 0; dsp < 2; ++dsp)
      qf[qs][dsp] = *(const bf16x8*)(qp + dsp * 32 + quad * 8);
#pragma unroll
    for (int rg = 0; rg < 4; ++rg)
      tq[qs][rg] = ts[n * SEQ + q0 + qs * 16 + quad * 4 + rg] * c2;
  }

  f32x4 accO[2][4] = {};
  f32x4 accL[2] = {};
  bf16x8 ones_b;
  {
    union { uint16_t u[8]; bf16x8 v; } t;
    uint16_t o = (l16 == 0) ? 0x3F80 : 0;   // bf16 1.0 in column 0 only
#pragma unroll
    for (int j = 0; j < 8; ++j) t.u[j] = o;
    ones_b = t.v;
  }
  uint16_t* Pw = &Plds[w][0];

  const uint16_t* Kbase = QKV + rowbase + DM + h * DH;
  const uint16_t* Vbase = QKV + rowbase + 2 * DM + h * DH;
  const int vr = tid & 63, vdb = (tid >> 6) * 16;
  uint4 vreg0, vreg1;

  // prologue: stage tile 0 (K via gload_lds, V via regs)
#pragma unroll
  for (int j = 0; j < 2; ++j) {
    int cid = j * 256 + w * 64 + lane;
    int r = cid >> 3, cc = cid & 7, c = cc ^ swz(r);
    async16(&Klds[(j * 256 + wu * 64) * 8], Kbase + (size_t)r * NQKV + c * 8);
  }
  vreg0 = *(const uint4*)(Vbase + (size_t)vr * NQKV + vdb);
  vreg1 = *(const uint4*)(Vbase + (size_t)vr * NQKV + vdb + 8);
  __syncthreads();                           // vmcnt drained: K0 in LDS, V0 in regs
  {
    union { uint4 v; uint16_t u[8]; } a0, a1;
    a0.v = vreg0; a1.v = vreg1;
#pragma unroll
    for (int j = 0; j < 8; ++j) Vt[(vdb + j) * 72 + vr] = a0.u[j];
#pragma unroll
    for (int j = 0; j < 8; ++j) Vt[(vdb + 8 + j) * 72 + vr] = a1.u[j];
  }
  __syncthreads();                           // tile 0 ready

  for (int it = 0; it < 8; ++it) {
    const int k0 = it * 64;
    // V(t+1) global->reg, issued before compute so HBM latency hides under it
    if (it < 7) {
      vreg0 = *(const uint4*)(Vbase + (size_t)(k0 + 64 + vr) * NQKV + vdb);
      vreg1 = *(const uint4*)(Vbase + (size_t)(k0 + 64 + vr) * NQKV + vdb + 8);
    }

#pragma unroll
    for (int kt = 0; kt < 2; ++kt) {
      uint16_t* Pk = Pw + kt * 1280;         // kt-indexed: cross-kt disjoint
      // S = Q K^T over this 32-col k-tile; columns interleaved: n -> k = 2*(lane&15)+ksu
      f32x4 s[2][2] = {};
      __builtin_amdgcn_s_setprio(1);
#pragma unroll
      for (int dsp = 0; dsp < 2; ++dsp) {
        bf16x8 kf[2];
#pragma unroll
        for (int ksu = 0; ksu < 2; ++ksu) {
          int r = kt * 32 + 2 * l16 + ksu;
          int c = (dsp * 4 + quad) ^ swz(r);
          kf[ksu] = *(const bf16x8*)&Klds[r * 64 + c * 8];
        }
#pragma unroll
        for (int qs = 0; qs < 2; ++qs)
#pragma unroll
          for (int ksu = 0; ksu < 2; ++ksu)
            s[qs][ksu] = MFMA16(qf[qs][dsp], kf[ksu], s[qs][ksu]);
      }
      __builtin_amdgcn_s_setprio(0);
      // bias + exp + pack to bf16 pairs -> Pk[q][k] (natural k order)
      float tk0 = tkl[k0 + kt * 32 + 2 * l16];
      float tk1 = tkl[k0 + kt * 32 + 2 * l16 + 1];
#pragma unroll
      for (int qs = 0; qs < 2; ++qs) {
#pragma unroll
        for (int rg = 0; rg < 4; ++rg) {
          float d0 = fabsf(tq[qs][rg] - tk0);   // v_sub; abs/neg ride as fma modifiers
          float d1 = fabsf(tq[qs][rg] - tk1);
          float p0 = __builtin_amdgcn_exp2f(fmaf(s[qs][0][rg], c1, -d0));
          float p1 = __builtin_amdgcn_exp2f(fmaf(s[qs][1][rg], c1, -d1));
          uint32_t u = (__float_as_uint(p0) >> 16) | (__float_as_uint(p1) & 0xFFFF0000u);
          *(uint32_t*)(Pk + (qs * 16 + quad * 4 + rg) * 40 + 2 * l16) = u;
        }
      }
      // fence: P-writes must precede cross-lane PV reads (compiler can't see alias)
      asm volatile("" ::: "memory");
      __builtin_amdgcn_sched_barrier(0);
      // PV (+ ones column for row-sums). Wave-private LDS, HW DS pipe is in-order.
      bf16x8 vb[4];
#pragma unroll
      for (int dt = 0; dt < 4; ++dt)
        vb[dt] = *(const bf16x8*)&Vt[(dt * 16 + l16) * 72 + kt * 32 + quad * 8];
      __builtin_amdgcn_s_setprio(1);
#pragma unroll
      for (int qs = 0; qs < 2; ++qs) {
        bf16x8 pa = *(const bf16x8*)(Pk + (qs * 16 + l16) * 40 + quad * 8);
#pragma unroll
        for (int dt = 0; dt < 4; ++dt)
          accO[qs][dt] = MFMA16(pa, vb[dt], accO[qs][dt]);
        accL[qs] = MFMA16(pa, ones_b, accL[qs]);
      }
      __builtin_amdgcn_s_setprio(0);
      // fence: PV reads must precede any later writes to Plds
      asm volatile("" ::: "memory");
      __builtin_amdgcn_sched_barrier(0);
    }

    __syncthreads();                         // all reads of Klds/Vt done; vmcnt drained
    if (it < 7) {
      {                                      // V(t+1) reg -> LDS transpose
        union { uint4 v; uint16_t u[8]; } a0, a1;
        a0.v = vreg0; a1.v = vreg1;
#pragma unroll
        for (int j = 0; j < 8; ++j) Vt[(vdb + j) * 72 + vr] = a0.u[j];
#pragma unroll
        for (int j = 0; j < 8; ++j) Vt[(vdb + 8 + j) * 72 + vr] = a1.u[j];
      }
#pragma unroll
      for (int j = 0; j < 2; ++j) {          // K(t+1) async into Klds
        int cid = j * 256 + w * 64 + lane;
        int r = cid >> 3, cc = cid & 7, c = cc ^ swz(r);
        async16(&Klds[(j * 256 + wu * 64) * 8],
                Kbase + (size_t)(k0 + 64 + r) * NQKV + c * 8);
      }
    }
    __syncthreads();                         // tile it+1 ready
  }
  // epilogue: O = accO / l ; l lives in column 0 (lane quad*16) of accL
#pragma unroll
  for (int qs = 0; qs < 2; ++qs) {
    float inv[4];
#pragma unroll
    for (int rg = 0; rg < 4; ++rg) {
      float lv = __shfl(accL[qs][rg], lane & 48, 64);
      inv[rg] = 1.0f / lv;
    }
#pragma unroll
    for (int dt = 0; dt < 4; ++dt) {
#pragma unroll
      for (int rg = 0; rg < 4; ++rg) {
        int qr = q0 + qs * 16 + quad * 4 + rg;
        float v = accO[qs][dt][rg] * inv[rg];
        Aout[(size_t)(n * SEQ + qr) * DM + h * DH + dt * 16 + l16] = f2bf(v);
      }
    }
  }
}

// ---------------- readout pooling (unchanged) ----------------
__global__ __launch_bounds__(256) void k_pool(
    const uint16_t* __restrict__ Out, const float* __restrict__ mask,
    const float* __restrict__ readout, float* __restrict__ dst) {
  __shared__ float rsl[64];
  __shared__ float ex[SEQ];
  __shared__ float red[4];
  __shared__ float part[8][64];
  int b = blockIdx.x;
  int n = b / NH, h = b % NH;
  int tid = threadIdx.x;
  if (tid < 64) rsl[tid] = readout[h * DH + tid];
  __syncthreads();

  float suml = 0.f;
  for (int l = tid; l < SEQ; l += 256) {
    const uint16_t* rowp = Out + (size_t)(n * SEQ + l) * DM + h * DH;
    float acc = 0.f;
#pragma unroll
    for (int c = 0; c < 8; ++c) {
      union { uint4 v; uint16_t u[8]; } t;
      t.v = *(const uint4*)(rowp + c * 8);
#pragma unroll
      for (int j = 0; j < 8; ++j)
        acc += __uint_as_float(((uint32_t)t.u[j]) << 16) * rsl[c * 8 + j];
    }
    float e = __builtin_amdgcn_exp2f(acc * (0.125f * 1.44269504f));
    e = (mask[n * SEQ + l] > 0.f) ? e : 0.f;
    ex[l] = e;
    suml += e;
  }
#pragma unroll
  for (int off = 32; off; off >>= 1) suml += __shfl_down(suml, off, 64);
  if ((tid & 63) == 0) red[tid >> 6] = suml;
  __syncthreads();
  float inv = 1.0f / (red[0] + red[1] + red[2] + red[3]);

  int d0 = (tid & 31) * 2, ch = tid >> 5;
  float a0 = 0.f, a1 = 0.f;
  for (int l = ch * 64; l < ch * 64 + 64; ++l) {
    uint32_t pv = *(const uint32_t*)(Out + (size_t)(n * SEQ + l) * DM + h * DH + d0);
    float e = ex[l];
    a0 = fmaf(__uint_as_float(pv << 16), e, a0);
    a1 = fmaf(__uint_as_float(pv & 0xFFFF0000u), e, a1);
  }
  part[ch][d0] = a0;
  part[ch][d0 + 1] = a1;
  __syncthreads();
  if (tid < 64) {
    float s = 0.f;
#pragma unroll
    for (int c = 0; c < 8; ++c) s += part[c][tid];
    dst[n * DM + h * DH + tid] = s * inv;
  }
}

// ---------------- launch ----------------
extern "C" void kernel_launch(void* const* d_in, const int* in_sizes, int n_in,
                              void* d_out, int out_size, void* d_ws, size_t ws_size,
                              hipStream_t stream) {
  const float* tokens  = (const float*)d_in[0];
  const float* ts      = (const float*)d_in[1];
  const float* mask    = (const float*)d_in[2];
  const float* Wq      = (const float*)d_in[3];
  const float* bq      = (const float*)d_in[4];
  const float* Wk      = (const float*)d_in[5];
  const float* bk      = (const float*)d_in[6];
  const float* Wv      = (const float*)d_in[7];
  const float* bv      = (const float*)d_in[8];
  const float* Wo      = (const float*)d_in[9];
  const float* bo      = (const float*)d_in[10];
  const float* readout = (const float*)d_in[11];

  char* ws = (char*)d_ws;
  uint16_t* X    = (uint16_t*)ws;                   // 50,331,648 B ; reused as attn_out
  uint16_t* Wqkv = (uint16_t*)(ws + 50331648);      //  3,538,944 B (packed)
  uint16_t* Wob  = (uint16_t*)(ws + 53870592);      //  1,179,648 B (packed)
  float*    bqkv = (float*)   (ws + 55050240);      //      9,216 B
  uint16_t* QKV  = (uint16_t*)(ws + 55059456);      // 150,994,944 B ; reused as Out
  uint16_t* attn = X;
  uint16_t* Outb = QKV;

  k_cvt<<<12288, 256, 0, stream>>>(tokens, Wq, Wk, Wv, Wo, bq, bk, bv, X, Wqkv, Wob, bqkv);
  k_gemm_bt<<<4608, 256, 0, stream>>>(X, Wqkv, bqkv, nullptr, QKV, NQKV, 18);
  k_attn<<<3072, 256, 0, stream>>>(QKV, ts, mask, attn);
  k_gemm_bt<<<1536, 256, 0, stream>>>(attn, Wob, bo, mask, Outb, DM, 6);
  k_pool<<<768, 256, 0, stream>>>(Outb, mask, readout, (float*)d_out);
}

// Round 9
// 478.406 us; speedup vs baseline: 1.1347x; 1.0067x over previous
//
#include <hip/hip_runtime.h>
#include <stdint.h>

#define AS1 __attribute__((address_space(1)))
#define AS3 __attribute__((address_space(3)))

typedef __bf16 bf16x8 __attribute__((ext_vector_type(8)));   // 4 VGPRs
typedef float  f32x4  __attribute__((ext_vector_type(4)));
typedef float  f32x16 __attribute__((ext_vector_type(16)));

#define MFMA16(a, b, c) __builtin_amdgcn_mfma_f32_16x16x32_bf16((a), (b), (c), 0, 0, 0)
#define MFMA32(a, b, c) __builtin_amdgcn_mfma_f32_32x32x16_bf16((a), (b), (c), 0, 0, 0)

// ---- constants for this problem ----
#define SEQ   512
#define NBAT  64
#define DM    768
#define NH    12
#define DH    64
#define NQKV  2304
#define NTOK  (NBAT * SEQ)   // 32768
#define NKB   12             // K=768 -> 12 K-tiles of 64

__device__ __forceinline__ uint16_t f2bf(float x) {          // fp32 -> bf16 RNE
  uint32_t u = __float_as_uint(x);
  return (uint16_t)((u + 0x7FFFu + ((u >> 16) & 1u)) >> 16);
}

__device__ __forceinline__ void async16(uint16_t* lds, const uint16_t* g) {
  // 16B global -> LDS direct (dest = wave-uniform base + lane*16)
  __builtin_amdgcn_global_load_lds((AS1 void*)(uintptr_t)(const void*)g,
                                   (AS3 void*)lds, 16, 0, 0);
}

// row->column XOR swizzle: conflict-free for the 32-row (l32/kh-split) MFMA
// fragment reads used below (measured 0 SQ_LDS_BANK_CONFLICT).
__device__ __forceinline__ int swz(int r) { return (r ^ (r >> 3)) & 7; }

// ---------------- merged converter + weight fragment-packing ----------------
// Packed layout: 16B chunk index ((g*NKB + kb)*4 + ks)*64 + lane holds
// B[row = g*32 + (lane&31)][k = kb*64 + ks*16 + (lane>>5)*8 .. +8) as bf16.
// A wave's per-(kb,ks) fragment load = 64 consecutive chunks = 1KB contiguous.
__global__ __launch_bounds__(256) void k_cvt(
    const float* __restrict__ tokens,
    const float* __restrict__ Wq, const float* __restrict__ Wk,
    const float* __restrict__ Wv, const float* __restrict__ Wo,
    const float* __restrict__ bq, const float* __restrict__ bk, const float* __restrict__ bv,
    uint16_t* __restrict__ X, uint16_t* __restrict__ Wqkv_pk, uint16_t* __restrict__ Wob_pk,
    float* __restrict__ bqkv) {
  int i = blockIdx.x * 256 + threadIdx.x;     // grid covers NTOK*DM/8 = 3,145,728
  {
    const float4* sp = (const float4*)tokens;
    float4 a = sp[2 * i], b = sp[2 * i + 1];
    union { uint16_t u[8]; uint4 v; } o;
    o.u[0] = f2bf(a.x); o.u[1] = f2bf(a.y); o.u[2] = f2bf(a.z); o.u[3] = f2bf(a.w);
    o.u[4] = f2bf(b.x); o.u[5] = f2bf(b.y); o.u[6] = f2bf(b.z); o.u[7] = f2bf(b.w);
    ((uint4*)X)[i] = o.v;
  }
  // Wqkv pack: 2304*768/8 = 221184 chunks
  if (i < 221184) {
    int lane = i & 63, ks = (i >> 6) & 3, kb = (i >> 8) % NKB, g = i / 3072;
    int row = g * 32 + (lane & 31);
    int k   = kb * 64 + ks * 16 + (lane >> 5) * 8;
    const float* src = (row < 768)  ? Wq + (size_t)row * 768 + k
                     : (row < 1536) ? Wk + (size_t)(row - 768) * 768 + k
                                    : Wv + (size_t)(row - 1536) * 768 + k;
    float4 a = *(const float4*)src, b = *(const float4*)(src + 4);
    union { uint16_t u[8]; uint4 v; } o;
    o.u[0] = f2bf(a.x); o.u[1] = f2bf(a.y); o.u[2] = f2bf(a.z); o.u[3] = f2bf(a.w);
    o.u[4] = f2bf(b.x); o.u[5] = f2bf(b.y); o.u[6] = f2bf(b.z); o.u[7] = f2bf(b.w);
    ((uint4*)Wqkv_pk)[i] = o.v;
  }
  // Wo pack: 768*768/8 = 73728 chunks
  if (i < 73728) {
    int lane = i & 63, ks = (i >> 6) & 3, kb = (i >> 8) % NKB, g = i / 3072;
    int row = g * 32 + (lane & 31);
    int k   = kb * 64 + ks * 16 + (lane >> 5) * 8;
    const float* src = Wo + (size_t)row * 768 + k;
    float4 a = *(const float4*)src, b = *(const float4*)(src + 4);
    union { uint16_t u[8]; uint4 v; } o;
    o.u[0] = f2bf(a.x); o.u[1] = f2bf(a.y); o.u[2] = f2bf(a.z); o.u[3] = f2bf(a.w);
    o.u[4] = f2bf(b.x); o.u[5] = f2bf(b.y); o.u[6] = f2bf(b.z); o.u[7] = f2bf(b.w);
    ((uint4*)Wob_pk)[i] = o.v;
  }
  if (i < 768) { bqkv[i] = bq[i]; bqkv[i + 768] = bk[i]; bqkv[i + 1536] = bv[i]; }
}

// ---------------- GEMM (R8-proven: 148.6us, occ 41%, 0 conflicts) ----------------
__global__ __launch_bounds__(256, 4) void k_gemm_bt(
    const uint16_t* __restrict__ A, const uint16_t* __restrict__ Bpk,
    const float* __restrict__ bias, const float* __restrict__ rowscale,
    uint16_t* __restrict__ C, int ldc, int ncol) {
  __shared__ uint16_t Alds[128 * 64];   // 16 KB
  const int tid  = threadIdx.x;
  const int w    = tid >> 6, lane = tid & 63;
  const int wu   = __builtin_amdgcn_readfirstlane(w);
  const int l32  = lane & 31, kh = lane >> 5;
  const int sup  = blockIdx.x / (32 * ncol);
  const int t    = blockIdx.x % (32 * ncol);
  const int row0 = (sup * 32 + (t & 31)) * 128, col0 = (t >> 5) * 128;
  const int wrow = (w >> 1) * 64,   wcol = (w & 1) * 64;

  // packed-B base for this wave: group g0 = col0/32 + (w&1)*2; +nt advances one group.
  const uint16_t* bw = Bpk + (size_t)((col0 >> 5) + (w & 1) * 2) * (NKB * 2048) + lane * 8;

  f32x16 acc[2][2] = {};
  for (int kb = 0; kb < NKB; ++kb) {
    __syncthreads();                              // prev iter's A-frag reads done
#pragma unroll
    for (int j = 0; j < 4; ++j) {                 // A: 1024 chunks
      int cid = j * 256 + w * 64 + lane;
      int r = cid >> 3, cc = cid & 7, c = cc ^ swz(r);
      async16(&Alds[(j * 256 + wu * 64) * 8],
              A + (size_t)(row0 + r) * 768 + kb * 64 + c * 8);
    }
    __syncthreads();                              // staging drained
#pragma unroll
    for (int ks = 0; ks < 4; ++ks) {              // 4 k-steps of 16
      // B fragments for this k-step: 2 contiguous 16B loads (L2 hits)
      bf16x8 bfr[2];
#pragma unroll
      for (int nt = 0; nt < 2; ++nt)
        bfr[nt] = *(const bf16x8*)(bw + (size_t)nt * (NKB * 2048) + (kb * 4 + ks) * 512);
      bf16x8 af[2];
#pragma unroll
      for (int mt = 0; mt < 2; ++mt) {
        int r = wrow + mt * 32 + l32;
        int c = (ks * 2 + kh) ^ swz(r);
        af[mt] = *(const bf16x8*)&Alds[r * 64 + c * 8];
      }
#pragma unroll
      for (int mt = 0; mt < 2; ++mt)
#pragma unroll
        for (int nt = 0; nt < 2; ++nt)
          acc[mt][nt] = MFMA32(af[mt], bfr[nt], acc[mt][nt]);
    }
  }
  // epilogue: 32x32 C/D layout: col=lane&31, row=(reg&3)+8*(reg>>2)+4*(lane>>5)
#pragma unroll
  for (int nt = 0; nt < 2; ++nt) {
    int col = col0 + wcol + nt * 32 + l32;
    float bv = bias[col];
#pragma unroll
    for (int mt = 0; mt < 2; ++mt) {
#pragma unroll
      for (int rg = 0; rg < 16; ++rg) {
        int row = row0 + wrow + mt * 32 + (rg & 3) + 8 * (rg >> 2) + 4 * kh;
        float v = acc[mt][nt][rg] + bv;
        if (rowscale) v *= rowscale[row];
        C[(size_t)row * ldc + col] = f2bf(v);
      }
    }
  }
}

// ---------------- fused attention: R9 qt-merge (8 waves, 2 q-tiles/block) ----------------
// 1536 blocks x 512 threads. Waves 0-3 handle q-tile qtp*2, waves 4-7 handle
// qtp*2+1; per-wave compute body identical to R7/R8 (proven). Per staged K/V
// tile, 256 q-rows now amortize the staging (was 128) -> staging bytes and
// serial K-staging windows per q-row HALVE. LDS 59KB -> 2 blocks/CU
// (16 waves/CU, same occupancy as before). K staging is one-shot (512 chunks
// = 512 threads); V-prefetch is one uint4 (8 d-cols) per thread.
__global__ __launch_bounds__(512) void k_attn(
    const uint16_t* __restrict__ QKV, const float* __restrict__ ts,
    const float* __restrict__ mask, uint16_t* __restrict__ Aout) {
  __shared__ uint16_t Klds[64 * 64];          // swizzled chunks, 8KB
  __shared__ uint16_t Vt[64 * 72];            // [d][k] padded, 9KB
  __shared__ uint16_t Plds[8][2 * 32 * 40];   // per-wave, kt-indexed, 40KB
  __shared__ float tkl[SEQ];                  // ts*c2, masked -> +3e38

  const int tid = threadIdx.x, w = tid >> 6, lane = tid & 63;
  const int wu = __builtin_amdgcn_readfirstlane(w);
  const int quad = lane >> 4, l16 = lane & 15;
  int b = blockIdx.x;
  int xcd = b & 7, i = b >> 3;               // i: 0..191
  int qtp = i & 1;                           // q-tile pair
  int hg = xcd * 96 + (i >> 1);              // 0..767
  int n = hg / NH, h = hg % NH;
  const int q0 = (qtp * 2 + (w >> 2)) * 128 + (w & 3) * 32;
  const size_t rowbase = (size_t)n * SEQ * NQKV;

  const float c1 = 0.125f * 1.44269504f;     // scale * log2(e)
  const float c2 = 1.44269504f / 300.0f;     // log2(e) / tau

  for (int l = tid; l < SEQ; l += 512) {
    float t = ts[n * SEQ + l] * c2;
    tkl[l] = (mask[n * SEQ + l] > 0.f) ? t : 3e38f;
  }

  // Q fragments (A-operand): A[m=lane&15][k=quad*8+j]
  bf16x8 qf[2][2];
  float tq[2][4];
#pragma unroll
  for (int qs = 0; qs < 2; ++qs) {
    int qr = q0 + qs * 16 + l16;
    const uint16_t* qp = QKV + rowbase + (size_t)qr * NQKV + h * DH;
#pragma unroll
    for (int dsp = 0; dsp < 2; ++dsp)
      qf[qs][dsp] = *(const bf16x8*)(qp + dsp * 32 + quad * 8);
#pragma unroll
    for (int rg = 0; rg < 4; ++rg)
      tq[qs][rg] = ts[n * SEQ + q0 + qs * 16 + quad * 4 + rg] * c2;
  }

  f32x4 accO[2][4] = {};
  f32x4 accL[2] = {};
  bf16x8 ones_b;
  {
    union { uint16_t u[8]; bf16x8 v; } t;
    uint16_t o = (l16 == 0) ? 0x3F80 : 0;   // bf16 1.0 in column 0 only
#pragma unroll
    for (int j = 0; j < 8; ++j) t.u[j] = o;
    ones_b = t.v;
  }
  uint16_t* Pw = &Plds[w][0];

  const uint16_t* Kbase = QKV + rowbase + DM + h * DH;
  const uint16_t* Vbase = QKV + rowbase + 2 * DM + h * DH;
  const int vr = tid & 63, vdb = (tid >> 6) * 8;   // 8 d-cols per thread
  uint4 vreg0;

  // prologue: stage tile 0 (K via gload_lds one-shot, V via regs)
  {
    int r = tid >> 3, c = (tid & 7) ^ swz(tid >> 3);
    async16(&Klds[wu * 64 * 8], Kbase + (size_t)r * NQKV + c * 8);
  }
  vreg0 = *(const uint4*)(Vbase + (size_t)vr * NQKV + vdb);
  __syncthreads();                           // vmcnt drained: K0 in LDS, V0 in regs
  {
    union { uint4 v; uint16_t u[8]; } a0;
    a0.v = vreg0;
#pragma unroll
    for (int j = 0; j < 8; ++j) Vt[(vdb + j) * 72 + vr] = a0.u[j];
  }
  __syncthreads();                           // tile 0 ready

  for (int it = 0; it < 8; ++it) {
    const int k0 = it * 64;
    // V(t+1) global->reg, issued before compute so HBM latency hides under it
    if (it < 7)
      vreg0 = *(const uint4*)(Vbase + (size_t)(k0 + 64 + vr) * NQKV + vdb);

#pragma unroll
    for (int kt = 0; kt < 2; ++kt) {
      uint16_t* Pk = Pw + kt * 1280;         // kt-indexed: cross-kt disjoint
      // S = Q K^T over this 32-col k-tile; columns interleaved: n -> k = 2*(lane&15)+ksu
      f32x4 s[2][2] = {};
      __builtin_amdgcn_s_setprio(1);
#pragma unroll
      for (int dsp = 0; dsp < 2; ++dsp) {
        bf16x8 kf[2];
#pragma unroll
        for (int ksu = 0; ksu < 2; ++ksu) {
          int r = kt * 32 + 2 * l16 + ksu;
          int c = (dsp * 4 + quad) ^ swz(r);
          kf[ksu] = *(const bf16x8*)&Klds[r * 64 + c * 8];
        }
#pragma unroll
        for (int qs = 0; qs < 2; ++qs)
#pragma unroll
          for (int ksu = 0; ksu < 2; ++ksu)
            s[qs][ksu] = MFMA16(qf[qs][dsp], kf[ksu], s[qs][ksu]);
      }
      __builtin_amdgcn_s_setprio(0);
      // bias + exp + pack to bf16 pairs -> Pk[q][k] (natural k order)
      float tk0 = tkl[k0 + kt * 32 + 2 * l16];
      float tk1 = tkl[k0 + kt * 32 + 2 * l16 + 1];
#pragma unroll
      for (int qs = 0; qs < 2; ++qs) {
#pragma unroll
        for (int rg = 0; rg < 4; ++rg) {
          float d0 = fabsf(tq[qs][rg] - tk0);   // v_sub; abs/neg ride as fma modifiers
          float d1 = fabsf(tq[qs][rg] - tk1);
          float p0 = __builtin_amdgcn_exp2f(fmaf(s[qs][0][rg], c1, -d0));
          float p1 = __builtin_amdgcn_exp2f(fmaf(s[qs][1][rg], c1, -d1));
          uint32_t u = (__float_as_uint(p0) >> 16) | (__float_as_uint(p1) & 0xFFFF0000u);
          *(uint32_t*)(Pk + (qs * 16 + quad * 4 + rg) * 40 + 2 * l16) = u;
        }
      }
      // fence: P-writes must precede cross-lane PV reads (compiler can't see alias)
      asm volatile("" ::: "memory");
      __builtin_amdgcn_sched_barrier(0);
      // PV (+ ones column for row-sums). Wave-private LDS, HW DS pipe is in-order.
      bf16x8 vb[4];
#pragma unroll
      for (int dt = 0; dt < 4; ++dt)
        vb[dt] = *(const bf16x8*)&Vt[(dt * 16 + l16) * 72 + kt * 32 + quad * 8];
      __builtin_amdgcn_s_setprio(1);
#pragma unroll
      for (int qs = 0; qs < 2; ++qs) {
        bf16x8 pa = *(const bf16x8*)(Pk + (qs * 16 + l16) * 40 + quad * 8);
#pragma unroll
        for (int dt = 0; dt < 4; ++dt)
          accO[qs][dt] = MFMA16(pa, vb[dt], accO[qs][dt]);
        accL[qs] = MFMA16(pa, ones_b, accL[qs]);
      }
      __builtin_amdgcn_s_setprio(0);
      // fence: PV reads must precede any later writes to Plds
      asm volatile("" ::: "memory");
      __builtin_amdgcn_sched_barrier(0);
    }

    __syncthreads();                         // all reads of Klds/Vt done; vmcnt drained
    if (it < 7) {
      {                                      // V(t+1) reg -> LDS transpose
        union { uint4 v; uint16_t u[8]; } a0;
        a0.v = vreg0;
#pragma unroll
        for (int j = 0; j < 8; ++j) Vt[(vdb + j) * 72 + vr] = a0.u[j];
      }
      {                                      // K(t+1) async into Klds (one-shot)
        int r = tid >> 3, c = (tid & 7) ^ swz(tid >> 3);
        async16(&Klds[wu * 64 * 8], Kbase + (size_t)(k0 + 64 + r) * NQKV + c * 8);
      }
    }
    __syncthreads();                         // tile it+1 ready
  }
  // epilogue: O = accO / l ; l lives in column 0 (lane quad*16) of accL
#pragma unroll
  for (int qs = 0; qs < 2; ++qs) {
    float inv[4];
#pragma unroll
    for (int rg = 0; rg < 4; ++rg) {
      float lv = __shfl(accL[qs][rg], lane & 48, 64);
      inv[rg] = 1.0f / lv;
    }
#pragma unroll
    for (int dt = 0; dt < 4; ++dt) {
#pragma unroll
      for (int rg = 0; rg < 4; ++rg) {
        int qr = q0 + qs * 16 + quad * 4 + rg;
        float v = accO[qs][dt][rg] * inv[rg];
        Aout[(size_t)(n * SEQ + qr) * DM + h * DH + dt * 16 + l16] = f2bf(v);
      }
    }
  }
}

// ---------------- readout pooling (unchanged) ----------------
__global__ __launch_bounds__(256) void k_pool(
    const uint16_t* __restrict__ Out, const float* __restrict__ mask,
    const float* __restrict__ readout, float* __restrict__ dst) {
  __shared__ float rsl[64];
  __shared__ float ex[SEQ];
  __shared__ float red[4];
  __shared__ float part[8][64];
  int b = blockIdx.x;
  int n = b / NH, h = b % NH;
  int tid = threadIdx.x;
  if (tid < 64) rsl[tid] = readout[h * DH + tid];
  __syncthreads();

  float suml = 0.f;
  for (int l = tid; l < SEQ; l += 256) {
    const uint16_t* rowp = Out + (size_t)(n * SEQ + l) * DM + h * DH;
    float acc = 0.f;
#pragma unroll
    for (int c = 0; c < 8; ++c) {
      union { uint4 v; uint16_t u[8]; } t;
      t.v = *(const uint4*)(rowp + c * 8);
#pragma unroll
      for (int j = 0; j < 8; ++j)
        acc += __uint_as_float(((uint32_t)t.u[j]) << 16) * rsl[c * 8 + j];
    }
    float e = __builtin_amdgcn_exp2f(acc * (0.125f * 1.44269504f));
    e = (mask[n * SEQ + l] > 0.f) ? e : 0.f;
    ex[l] = e;
    suml += e;
  }
#pragma unroll
  for (int off = 32; off; off >>= 1) suml += __shfl_down(suml, off, 64);
  if ((tid & 63) == 0) red[tid >> 6] = suml;
  __syncthreads();
  float inv = 1.0f / (red[0] + red[1] + red[2] + red[3]);

  int d0 = (tid & 31) * 2, ch = tid >> 5;
  float a0 = 0.f, a1 = 0.f;
  for (int l = ch * 64; l < ch * 64 + 64; ++l) {
    uint32_t pv = *(const uint32_t*)(Out + (size_t)(n * SEQ + l) * DM + h * DH + d0);
    float e = ex[l];
    a0 = fmaf(__uint_as_float(pv << 16), e, a0);
    a1 = fmaf(__uint_as_float(pv & 0xFFFF0000u), e, a1);
  }
  part[ch][d0] = a0;
  part[ch][d0 + 1] = a1;
  __syncthreads();
  if (tid < 64) {
    float s = 0.f;
#pragma unroll
    for (int c = 0; c < 8; ++c) s += part[c][tid];
    dst[n * DM + h * DH + tid] = s * inv;
  }
}

// ---------------- launch ----------------
extern "C" void kernel_launch(void* const* d_in, const int* in_sizes, int n_in,
                              void* d_out, int out_size, void* d_ws, size_t ws_size,
                              hipStream_t stream) {
  const float* tokens  = (const float*)d_in[0];
  const float* ts      = (const float*)d_in[1];
  const float* mask    = (const float*)d_in[2];
  const float* Wq      = (const float*)d_in[3];
  const float* bq      = (const float*)d_in[4];
  const float* Wk      = (const float*)d_in[5];
  const float* bk      = (const float*)d_in[6];
  const float* Wv      = (const float*)d_in[7];
  const float* bv      = (const float*)d_in[8];
  const float* Wo      = (const float*)d_in[9];
  const float* bo      = (const float*)d_in[10];
  const float* readout = (const float*)d_in[11];

  char* ws = (char*)d_ws;
  uint16_t* X    = (uint16_t*)ws;                   // 50,331,648 B ; reused as attn_out
  uint16_t* Wqkv = (uint16_t*)(ws + 50331648);      //  3,538,944 B (packed)
  uint16_t* Wob  = (uint16_t*)(ws + 53870592);      //  1,179,648 B (packed)
  float*    bqkv = (float*)   (ws + 55050240);      //      9,216 B
  uint16_t* QKV  = (uint16_t*)(ws + 55059456);      // 150,994,944 B ; reused as Out
  uint16_t* attn = X;
  uint16_t* Outb = QKV;

  k_cvt<<<12288, 256, 0, stream>>>(tokens, Wq, Wk, Wv, Wo, bq, bk, bv, X, Wqkv, Wob, bqkv);
  k_gemm_bt<<<4608, 256, 0, stream>>>(X, Wqkv, bqkv, nullptr, QKV, NQKV, 18);
  k_attn<<<1536, 512, 0, stream>>>(QKV, ts, mask, attn);
  k_gemm_bt<<<1536, 256, 0, stream>>>(attn, Wob, bo, mask, Outb, DM, 6);
  k_pool<<<768, 256, 0, stream>>>(Outb, mask, readout, (float*)d_out);
}

// Round 10
// 470.236 us; speedup vs baseline: 1.1544x; 1.0174x over previous
//
#include <hip/hip_runtime.h>
#include <stdint.h>

#define AS1 __attribute__((address_space(1)))
#define AS3 __attribute__((address_space(3)))

typedef __bf16 bf16x8 __attribute__((ext_vector_type(8)));   // 4 VGPRs
typedef float  f32x4  __attribute__((ext_vector_type(4)));
typedef float  f32x16 __attribute__((ext_vector_type(16)));

#define MFMA16(a, b, c) __builtin_amdgcn_mfma_f32_16x16x32_bf16((a), (b), (c), 0, 0, 0)
#define MFMA32(a, b, c) __builtin_amdgcn_mfma_f32_32x32x16_bf16((a), (b), (c), 0, 0, 0)

// ---- constants for this problem ----
#define SEQ   512
#define NBAT  64
#define DM    768
#define NH    12
#define DH    64
#define NQKV  2304
#define NTOK  (NBAT * SEQ)   // 32768
#define NKB   12             // K=768 -> 12 K-tiles of 64

__device__ __forceinline__ uint16_t f2bf(float x) {          // fp32 -> bf16 RNE
  uint32_t u = __float_as_uint(x);
  return (uint16_t)((u + 0x7FFFu + ((u >> 16) & 1u)) >> 16);
}

__device__ __forceinline__ void async16(uint16_t* lds, const uint16_t* g) {
  // 16B global -> LDS direct (dest = wave-uniform base + lane*16)
  __builtin_amdgcn_global_load_lds((AS1 void*)(uintptr_t)(const void*)g,
                                   (AS3 void*)lds, 16, 0, 0);
}

// row->column XOR swizzle: conflict-free for the 32-row (l32/kh-split) MFMA
// fragment reads used below (measured 0 SQ_LDS_BANK_CONFLICT).
__device__ __forceinline__ int swz(int r) { return (r ^ (r >> 3)) & 7; }

// ---------------- merged converter + weight fragment-packing ----------------
__global__ __launch_bounds__(256) void k_cvt(
    const float* __restrict__ tokens,
    const float* __restrict__ Wq, const float* __restrict__ Wk,
    const float* __restrict__ Wv, const float* __restrict__ Wo,
    const float* __restrict__ bq, const float* __restrict__ bk, const float* __restrict__ bv,
    uint16_t* __restrict__ X, uint16_t* __restrict__ Wqkv_pk, uint16_t* __restrict__ Wob_pk,
    float* __restrict__ bqkv) {
  int i = blockIdx.x * 256 + threadIdx.x;     // grid covers NTOK*DM/8 = 3,145,728
  {
    const float4* sp = (const float4*)tokens;
    float4 a = sp[2 * i], b = sp[2 * i + 1];
    union { uint16_t u[8]; uint4 v; } o;
    o.u[0] = f2bf(a.x); o.u[1] = f2bf(a.y); o.u[2] = f2bf(a.z); o.u[3] = f2bf(a.w);
    o.u[4] = f2bf(b.x); o.u[5] = f2bf(b.y); o.u[6] = f2bf(b.z); o.u[7] = f2bf(b.w);
    ((uint4*)X)[i] = o.v;
  }
  // Wqkv pack: 2304*768/8 = 221184 chunks
  if (i < 221184) {
    int lane = i & 63, ks = (i >> 6) & 3, kb = (i >> 8) % NKB, g = i / 3072;
    int row = g * 32 + (lane & 31);
    int k   = kb * 64 + ks * 16 + (lane >> 5) * 8;
    const float* src = (row < 768)  ? Wq + (size_t)row * 768 + k
                     : (row < 1536) ? Wk + (size_t)(row - 768) * 768 + k
                                    : Wv + (size_t)(row - 1536) * 768 + k;
    float4 a = *(const float4*)src, b = *(const float4*)(src + 4);
    union { uint16_t u[8]; uint4 v; } o;
    o.u[0] = f2bf(a.x); o.u[1] = f2bf(a.y); o.u[2] = f2bf(a.z); o.u[3] = f2bf(a.w);
    o.u[4] = f2bf(b.x); o.u[5] = f2bf(b.y); o.u[6] = f2bf(b.z); o.u[7] = f2bf(b.w);
    ((uint4*)Wqkv_pk)[i] = o.v;
  }
  // Wo pack: 768*768/8 = 73728 chunks
  if (i < 73728) {
    int lane = i & 63, ks = (i >> 6) & 3, kb = (i >> 8) % NKB, g = i / 3072;
    int row = g * 32 + (lane & 31);
    int k   = kb * 64 + ks * 16 + (lane >> 5) * 8;
    const float* src = Wo + (size_t)row * 768 + k;
    float4 a = *(const float4*)src, b = *(const float4*)(src + 4);
    union { uint16_t u[8]; uint4 v; } o;
    o.u[0] = f2bf(a.x); o.u[1] = f2bf(a.y); o.u[2] = f2bf(a.z); o.u[3] = f2bf(a.w);
    o.u[4] = f2bf(b.x); o.u[5] = f2bf(b.y); o.u[6] = f2bf(b.z); o.u[7] = f2bf(b.w);
    ((uint4*)Wob_pk)[i] = o.v;
  }
  if (i < 768) { bqkv[i] = bq[i]; bqkv[i + 768] = bk[i]; bqkv[i + 1536] = bv[i]; }
}

// ---------------- GEMM (R8-proven: ~147us, occ 41%, 0 conflicts) ----------------
__global__ __launch_bounds__(256, 4) void k_gemm_bt(
    const uint16_t* __restrict__ A, const uint16_t* __restrict__ Bpk,
    const float* __restrict__ bias, const float* __restrict__ rowscale,
    uint16_t* __restrict__ C, int ldc, int ncol) {
  __shared__ uint16_t Alds[128 * 64];   // 16 KB
  const int tid  = threadIdx.x;
  const int w    = tid >> 6, lane = tid & 63;
  const int wu   = __builtin_amdgcn_readfirstlane(w);
  const int l32  = lane & 31, kh = lane >> 5;
  const int sup  = blockIdx.x / (32 * ncol);
  const int t    = blockIdx.x % (32 * ncol);
  const int row0 = (sup * 32 + (t & 31)) * 128, col0 = (t >> 5) * 128;
  const int wrow = (w >> 1) * 64,   wcol = (w & 1) * 64;

  // packed-B base for this wave: group g0 = col0/32 + (w&1)*2; +nt advances one group.
  const uint16_t* bw = Bpk + (size_t)((col0 >> 5) + (w & 1) * 2) * (NKB * 2048) + lane * 8;

  f32x16 acc[2][2] = {};
  for (int kb = 0; kb < NKB; ++kb) {
    __syncthreads();                              // prev iter's A-frag reads done
#pragma unroll
    for (int j = 0; j < 4; ++j) {                 // A: 1024 chunks
      int cid = j * 256 + w * 64 + lane;
      int r = cid >> 3, cc = cid & 7, c = cc ^ swz(r);
      async16(&Alds[(j * 256 + wu * 64) * 8],
              A + (size_t)(row0 + r) * 768 + kb * 64 + c * 8);
    }
    __syncthreads();                              // staging drained
#pragma unroll
    for (int ks = 0; ks < 4; ++ks) {              // 4 k-steps of 16
      // B fragments for this k-step: 2 contiguous 16B loads (L2 hits)
      bf16x8 bfr[2];
#pragma unroll
      for (int nt = 0; nt < 2; ++nt)
        bfr[nt] = *(const bf16x8*)(bw + (size_t)nt * (NKB * 2048) + (kb * 4 + ks) * 512);
      bf16x8 af[2];
#pragma unroll
      for (int mt = 0; mt < 2; ++mt) {
        int r = wrow + mt * 32 + l32;
        int c = (ks * 2 + kh) ^ swz(r);
        af[mt] = *(const bf16x8*)&Alds[r * 64 + c * 8];
      }
#pragma unroll
      for (int mt = 0; mt < 2; ++mt)
#pragma unroll
        for (int nt = 0; nt < 2; ++nt)
          acc[mt][nt] = MFMA32(af[mt], bfr[nt], acc[mt][nt]);
    }
  }
  // epilogue: 32x32 C/D layout: col=lane&31, row=(reg&3)+8*(reg>>2)+4*(lane>>5)
#pragma unroll
  for (int nt = 0; nt < 2; ++nt) {
    int col = col0 + wcol + nt * 32 + l32;
    float bv = bias[col];
#pragma unroll
    for (int mt = 0; mt < 2; ++mt) {
#pragma unroll
      for (int rg = 0; rg < 16; ++rg) {
        int row = row0 + wrow + mt * 32 + (rg & 3) + 8 * (rg >> 2) + 4 * kh;
        float v = acc[mt][nt][rg] + bv;
        if (rowscale) v *= rowscale[row];
        C[(size_t)row * ldc + col] = f2bf(v);
      }
    }
  }
}

// ---------------- fused attention: R10 = R9 qt-merge + K double-buffer, no fences ----------------
// Per tile t: K(t+1) gload_lds -> Klds[cur^1] AND V(t+1)->reg issued BEFORE
// compute(t), so the barrier's vmcnt drain has a full compute phase of cover
// (R9 issued K between the barriers -> serial ~500-900cyc x8/block).
// WAR: Klds[cur^1] was last read in it-1's compute, two barriers before the
// re-issue. Fences/sched_barriers removed (R5's corruption was the vdb
// address bug, not reordering; P-write->read order is preserved by may-alias
// + the in-order DS pipe — the R0-proven configuration), enabling cross-kt
// ILP (kt=1 QK^T can overlap kt=0 PV). LDS 67KB -> 2 blocks/CU.
__global__ __launch_bounds__(512) void k_attn(
    const uint16_t* __restrict__ QKV, const float* __restrict__ ts,
    const float* __restrict__ mask, uint16_t* __restrict__ Aout) {
  __shared__ uint16_t Klds[2][64 * 64];       // swizzled chunks, 2 x 8KB
  __shared__ uint16_t Vt[64 * 72];            // [d][k] padded, 9KB
  __shared__ uint16_t Plds[8][2 * 32 * 40];   // per-wave, kt-indexed, 40KB
  __shared__ float tkl[SEQ];                  // ts*c2, masked -> +3e38

  const int tid = threadIdx.x, w = tid >> 6, lane = tid & 63;
  const int wu = __builtin_amdgcn_readfirstlane(w);
  const int quad = lane >> 4, l16 = lane & 15;
  int b = blockIdx.x;
  int xcd = b & 7, i = b >> 3;               // i: 0..191
  int qtp = i & 1;                           // q-tile pair
  int hg = xcd * 96 + (i >> 1);              // 0..767
  int n = hg / NH, h = hg % NH;
  const int q0 = (qtp * 2 + (w >> 2)) * 128 + (w & 3) * 32;
  const size_t rowbase = (size_t)n * SEQ * NQKV;

  const float c1 = 0.125f * 1.44269504f;     // scale * log2(e)
  const float c2 = 1.44269504f / 300.0f;     // log2(e) / tau

  for (int l = tid; l < SEQ; l += 512) {
    float t = ts[n * SEQ + l] * c2;
    tkl[l] = (mask[n * SEQ + l] > 0.f) ? t : 3e38f;
  }

  // Q fragments (A-operand): A[m=lane&15][k=quad*8+j]
  bf16x8 qf[2][2];
  float tq[2][4];
#pragma unroll
  for (int qs = 0; qs < 2; ++qs) {
    int qr = q0 + qs * 16 + l16;
    const uint16_t* qp = QKV + rowbase + (size_t)qr * NQKV + h * DH;
#pragma unroll
    for (int dsp = 0; dsp < 2; ++dsp)
      qf[qs][dsp] = *(const bf16x8*)(qp + dsp * 32 + quad * 8);
#pragma unroll
    for (int rg = 0; rg < 4; ++rg)
      tq[qs][rg] = ts[n * SEQ + q0 + qs * 16 + quad * 4 + rg] * c2;
  }

  f32x4 accO[2][4] = {};
  f32x4 accL[2] = {};
  bf16x8 ones_b;
  {
    union { uint16_t u[8]; bf16x8 v; } t;
    uint16_t o = (l16 == 0) ? 0x3F80 : 0;   // bf16 1.0 in column 0 only
#pragma unroll
    for (int j = 0; j < 8; ++j) t.u[j] = o;
    ones_b = t.v;
  }
  uint16_t* Pw = &Plds[w][0];

  const uint16_t* Kbase = QKV + rowbase + DM + h * DH;
  const uint16_t* Vbase = QKV + rowbase + 2 * DM + h * DH;
  const int vr = tid & 63, vdb = (tid >> 6) * 8;   // 8 d-cols per thread
  const int kr = tid >> 3, kc = (tid & 7) ^ swz(tid >> 3);
  uint4 vreg0;

  // prologue: stage tile 0 (K via gload_lds one-shot, V via regs)
  async16(&Klds[0][wu * 64 * 8], Kbase + (size_t)kr * NQKV + kc * 8);
  vreg0 = *(const uint4*)(Vbase + (size_t)vr * NQKV + vdb);
  __syncthreads();                           // vmcnt drained: K0 in LDS, V0 in regs
  {
    union { uint4 v; uint16_t u[8]; } a0;
    a0.v = vreg0;
#pragma unroll
    for (int j = 0; j < 8; ++j) Vt[(vdb + j) * 72 + vr] = a0.u[j];
  }
  __syncthreads();                           // tile 0 ready

  for (int it = 0; it < 8; ++it) {
    const int k0 = it * 64, cur = it & 1;
    // prefetch tile it+1 BEFORE compute: K async into the other buffer, V to regs
    if (it < 7) {
      async16(&Klds[cur ^ 1][wu * 64 * 8],
              Kbase + (size_t)(k0 + 64 + kr) * NQKV + kc * 8);
      vreg0 = *(const uint4*)(Vbase + (size_t)(k0 + 64 + vr) * NQKV + vdb);
    }

#pragma unroll
    for (int kt = 0; kt < 2; ++kt) {
      uint16_t* Pk = Pw + kt * 1280;         // kt-indexed: cross-kt disjoint
      // S = Q K^T over this 32-col k-tile; columns interleaved: n -> k = 2*(lane&15)+ksu
      f32x4 s[2][2] = {};
      __builtin_amdgcn_s_setprio(1);
#pragma unroll
      for (int dsp = 0; dsp < 2; ++dsp) {
        bf16x8 kf[2];
#pragma unroll
        for (int ksu = 0; ksu < 2; ++ksu) {
          int r = kt * 32 + 2 * l16 + ksu;
          int c = (dsp * 4 + quad) ^ swz(r);
          kf[ksu] = *(const bf16x8*)&Klds[cur][r * 64 + c * 8];
        }
#pragma unroll
        for (int qs = 0; qs < 2; ++qs)
#pragma unroll
          for (int ksu = 0; ksu < 2; ++ksu)
            s[qs][ksu] = MFMA16(qf[qs][dsp], kf[ksu], s[qs][ksu]);
      }
      __builtin_amdgcn_s_setprio(0);
      // bias + exp + pack to bf16 pairs -> Pk[q][k] (natural k order)
      float tk0 = tkl[k0 + kt * 32 + 2 * l16];
      float tk1 = tkl[k0 + kt * 32 + 2 * l16 + 1];
#pragma unroll
      for (int qs = 0; qs < 2; ++qs) {
#pragma unroll
        for (int rg = 0; rg < 4; ++rg) {
          float d0 = fabsf(tq[qs][rg] - tk0);   // v_sub; abs/neg ride as fma modifiers
          float d1 = fabsf(tq[qs][rg] - tk1);
          float p0 = __builtin_amdgcn_exp2f(fmaf(s[qs][0][rg], c1, -d0));
          float p1 = __builtin_amdgcn_exp2f(fmaf(s[qs][1][rg], c1, -d1));
          uint32_t u = (__float_as_uint(p0) >> 16) | (__float_as_uint(p1) & 0xFFFF0000u);
          *(uint32_t*)(Pk + (qs * 16 + quad * 4 + rg) * 40 + 2 * l16) = u;
        }
      }
      // PV (+ ones column for row-sums). Wave-private LDS: may-alias keeps the
      // P write->read order; DS pipe is in-order per wave (R0-proven, no fence).
      bf16x8 vb[4];
#pragma unroll
      for (int dt = 0; dt < 4; ++dt)
        vb[dt] = *(const bf16x8*)&Vt[(dt * 16 + l16) * 72 + kt * 32 + quad * 8];
      __builtin_amdgcn_s_setprio(1);
#pragma unroll
      for (int qs = 0; qs < 2; ++qs) {
        bf16x8 pa = *(const bf16x8*)(Pk + (qs * 16 + l16) * 40 + quad * 8);
#pragma unroll
        for (int dt = 0; dt < 4; ++dt)
          accO[qs][dt] = MFMA16(pa, vb[dt], accO[qs][dt]);
        accL[qs] = MFMA16(pa, ones_b, accL[qs]);
      }
      __builtin_amdgcn_s_setprio(0);
    }

    __syncthreads();                 // reads of Klds[cur]/Vt done; vmcnt drained (K/V it+1 ready)
    if (it < 7) {
      union { uint4 v; uint16_t u[8]; } a0;
      a0.v = vreg0;
#pragma unroll
      for (int j = 0; j < 8; ++j) Vt[(vdb + j) * 72 + vr] = a0.u[j];
    }
    __syncthreads();                 // Vt(it+1) ready; Klds[cur^1] ready
  }
  // epilogue: O = accO / l ; l lives in column 0 (lane quad*16) of accL
#pragma unroll
  for (int qs = 0; qs < 2; ++qs) {
    float inv[4];
#pragma unroll
    for (int rg = 0; rg < 4; ++rg) {
      float lv = __shfl(accL[qs][rg], lane & 48, 64);
      inv[rg] = 1.0f / lv;
    }
#pragma unroll
    for (int dt = 0; dt < 4; ++dt) {
#pragma unroll
      for (int rg = 0; rg < 4; ++rg) {
        int qr = q0 + qs * 16 + quad * 4 + rg;
        float v = accO[qs][dt][rg] * inv[rg];
        Aout[(size_t)(n * SEQ + qr) * DM + h * DH + dt * 16 + l16] = f2bf(v);
      }
    }
  }
}

// ---------------- readout pooling (unchanged) ----------------
__global__ __launch_bounds__(256) void k_pool(
    const uint16_t* __restrict__ Out, const float* __restrict__ mask,
    const float* __restrict__ readout, float* __restrict__ dst) {
  __shared__ float rsl[64];
  __shared__ float ex[SEQ];
  __shared__ float red[4];
  __shared__ float part[8][64];
  int b = blockIdx.x;
  int n = b / NH, h = b % NH;
  int tid = threadIdx.x;
  if (tid < 64) rsl[tid] = readout[h * DH + tid];
  __syncthreads();

  float suml = 0.f;
  for (int l = tid; l < SEQ; l += 256) {
    const uint16_t* rowp = Out + (size_t)(n * SEQ + l) * DM + h * DH;
    float acc = 0.f;
#pragma unroll
    for (int c = 0; c < 8; ++c) {
      union { uint4 v; uint16_t u[8]; } t;
      t.v = *(const uint4*)(rowp + c * 8);
#pragma unroll
      for (int j = 0; j < 8; ++j)
        acc += __uint_as_float(((uint32_t)t.u[j]) << 16) * rsl[c * 8 + j];
    }
    float e = __builtin_amdgcn_exp2f(acc * (0.125f * 1.44269504f));
    e = (mask[n * SEQ + l] > 0.f) ? e : 0.f;
    ex[l] = e;
    suml += e;
  }
#pragma unroll
  for (int off = 32; off; off >>= 1) suml += __shfl_down(suml, off, 64);
  if ((tid & 63) == 0) red[tid >> 6] = suml;
  __syncthreads();
  float inv = 1.0f / (red[0] + red[1] + red[2] + red[3]);

  int d0 = (tid & 31) * 2, ch = tid >> 5;
  float a0 = 0.f, a1 = 0.f;
  for (int l = ch * 64; l < ch * 64 + 64; ++l) {
    uint32_t pv = *(const uint32_t*)(Out + (size_t)(n * SEQ + l) * DM + h * DH + d0);
    float e = ex[l];
    a0 = fmaf(__uint_as_float(pv << 16), e, a0);
    a1 = fmaf(__uint_as_float(pv & 0xFFFF0000u), e, a1);
  }
  part[ch][d0] = a0;
  part[ch][d0 + 1] = a1;
  __syncthreads();
  if (tid < 64) {
    float s = 0.f;
#pragma unroll
    for (int c = 0; c < 8; ++c) s += part[c][tid];
    dst[n * DM + h * DH + tid] = s * inv;
  }
}

// ---------------- launch ----------------
extern "C" void kernel_launch(void* const* d_in, const int* in_sizes, int n_in,
                              void* d_out, int out_size, void* d_ws, size_t ws_size,
                              hipStream_t stream) {
  const float* tokens  = (const float*)d_in[0];
  const float* ts      = (const float*)d_in[1];
  const float* mask    = (const float*)d_in[2];
  const float* Wq      = (const float*)d_in[3];
  const float* bq      = (const float*)d_in[4];
  const float* Wk      = (const float*)d_in[5];
  const float* bk      = (const float*)d_in[6];
  const float* Wv      = (const float*)d_in[7];
  const float* bv      = (const float*)d_in[8];
  const float* Wo      = (const float*)d_in[9];
  const float* bo      = (const float*)d_in[10];
  const float* readout = (const float*)d_in[11];

  char* ws = (char*)d_ws;
  uint16_t* X    = (uint16_t*)ws;                   // 50,331,648 B ; reused as attn_out
  uint16_t* Wqkv = (uint16_t*)(ws + 50331648);      //  3,538,944 B (packed)
  uint16_t* Wob  = (uint16_t*)(ws + 53870592);      //  1,179,648 B (packed)
  float*    bqkv = (float*)   (ws + 55050240);      //      9,216 B
  uint16_t* QKV  = (uint16_t*)(ws + 55059456);      // 150,994,944 B ; reused as Out
  uint16_t* attn = X;
  uint16_t* Outb = QKV;

  k_cvt<<<12288, 256, 0, stream>>>(tokens, Wq, Wk, Wv, Wo, bq, bk, bv, X, Wqkv, Wob, bqkv);
  k_gemm_bt<<<4608, 256, 0, stream>>>(X, Wqkv, bqkv, nullptr, QKV, NQKV, 18);
  k_attn<<<1536, 512, 0, stream>>>(QKV, ts, mask, attn);
  k_gemm_bt<<<1536, 256, 0, stream>>>(attn, Wob, bo, mask, Outb, DM, 6);
  k_pool<<<768, 256, 0, stream>>>(Outb, mask, readout, (float*)d_out);
}